// Round 7
// baseline (1977.818 us; speedup 1.0000x reference)
//
#include <hip/hip_runtime.h>
#include <hip/hip_bf16.h>
#include <math.h>

#define D_ 1024
#define C_ 512
#define H_ 16
#define DH_ 64
#define P_ 16
#define FF_ 4096
#define S_ 4096
#define B_ 4
#define NC_ 8
#define KP_ 72   // attn LDS pitch (shorts)

typedef __attribute__((ext_vector_type(8))) short short8;
typedef __attribute__((ext_vector_type(4))) float floatx4;

__device__ __forceinline__ float sigmoidf_(float x) { return 1.0f / (1.0f + __expf(-x)); }
__device__ __forceinline__ unsigned short f2b(float x) {
    __hip_bfloat16 h = __float2bfloat16(x);
    return __builtin_bit_cast(unsigned short, h);
}
__device__ __forceinline__ float b2f(unsigned short u) {
    __hip_bfloat16 h = __builtin_bit_cast(__hip_bfloat16, u);
    return __bfloat162float(h);
}
// async global->LDS 16B: LDS dst = wave-uniform base + lane*16
__device__ __forceinline__ void async_cp16(const unsigned short* g, short* l) {
    __builtin_amdgcn_global_load_lds(
        (const __attribute__((address_space(1))) void*)g,
        (__attribute__((address_space(3))) void*)l, 16, 0, 0);
}
__device__ __forceinline__ void wait_vm8()   { asm volatile("s_waitcnt vmcnt(8)" ::: "memory"); }
__device__ __forceinline__ void wait_vm6()   { asm volatile("s_waitcnt vmcnt(6)" ::: "memory"); }
__device__ __forceinline__ void wait_vm0()   { asm volatile("s_waitcnt vmcnt(0)" ::: "memory"); }
__device__ __forceinline__ void wait_lgkm0() { asm volatile("s_waitcnt lgkmcnt(0)" ::: "memory"); }
__device__ __forceinline__ void wait_lgkm8() { asm volatile("s_waitcnt lgkmcnt(8)" ::: "memory"); }
#define SBAR() __builtin_amdgcn_sched_barrier(0)

// ---------------------------------------------------------------- LayerNorm (fp32 in, bf16 out)
__global__ __launch_bounds__(256) void ln_kernel(
    const float* __restrict__ x, long long xBatchStride, int rowsPerBatch,
    const float* __restrict__ add,
    const float* __restrict__ g, const float* __restrict__ beta,
    unsigned short* __restrict__ out)
{
    __shared__ float sbuf[4];
    int row = blockIdx.x;
    int bb = row / rowsPerBatch, s = row - bb * rowsPerBatch;
    const float* xr = x + (long long)bb * xBatchStride + (long long)s * D_;
    int t = threadIdx.x;
    float v[4];
    float4 xv = *(const float4*)(xr + t * 4);
    v[0] = xv.x; v[1] = xv.y; v[2] = xv.z; v[3] = xv.w;
    if (add) {
        float4 av = *(const float4*)(add + (long long)row * D_ + t * 4);
        v[0] += av.x; v[1] += av.y; v[2] += av.z; v[3] += av.w;
    }
    float ls = v[0] + v[1] + v[2] + v[3];
    #pragma unroll
    for (int off = 32; off >= 1; off >>= 1) ls += __shfl_down(ls, off, 64);
    if ((t & 63) == 0) sbuf[t >> 6] = ls;
    __syncthreads();
    float mean = (sbuf[0] + sbuf[1] + sbuf[2] + sbuf[3]) * (1.0f / D_);
    __syncthreads();
    float lv = 0.f;
    #pragma unroll
    for (int i = 0; i < 4; i++) { float d = v[i] - mean; lv += d * d; }
    #pragma unroll
    for (int off = 32; off >= 1; off >>= 1) lv += __shfl_down(lv, off, 64);
    if ((t & 63) == 0) sbuf[t >> 6] = lv;
    __syncthreads();
    float var = (sbuf[0] + sbuf[1] + sbuf[2] + sbuf[3]) * (1.0f / D_);
    float r = rsqrtf(var + 1e-5f);
    unsigned short* orow = out + (long long)row * D_;
    #pragma unroll
    for (int i = 0; i < 4; i++) {
        int c = t * 4 + i;
        orow[c] = f2b((v[i] - mean) * r * g[c] + beta[c]);
    }
}

// ---------------------------------------------------------------- fused gate-combine + LN3
__global__ __launch_bounds__(256) void gate_ln_kernel(
    const float* __restrict__ x, long long xBS, int gcShift,
    const float* __restrict__ gbuf, const float* __restrict__ aoW,
    const float* __restrict__ mctx,
    const float* __restrict__ g3, const float* __restrict__ b3,
    float* __restrict__ og, unsigned short* __restrict__ lnout)
{
    __shared__ float sbuf[4];
    int row = blockIdx.x;
    int bb = row >> gcShift, s = row & ((1 << gcShift) - 1);
    int t = threadIdx.x;
    long long fbase = (long long)row * D_ + t * 4;
    long long xbase = (long long)bb * xBS + (long long)s * D_ + t * 4;
    float4 xv = *(const float4*)(x + xbase);
    float4 gv = *(const float4*)(gbuf + fbase);
    float4 av = *(const float4*)(aoW + fbase);
    float4 mv = *(const float4*)(mctx + fbase);
    float v[4];
    {
        float gg;
        gg = sigmoidf_(gv.x); v[0] = xv.x + gg * av.x + (1.0f - gg) * mv.x;
        gg = sigmoidf_(gv.y); v[1] = xv.y + gg * av.y + (1.0f - gg) * mv.y;
        gg = sigmoidf_(gv.z); v[2] = xv.z + gg * av.z + (1.0f - gg) * mv.z;
        gg = sigmoidf_(gv.w); v[3] = xv.w + gg * av.w + (1.0f - gg) * mv.w;
    }
    *(float4*)(og + xbase) = (float4){v[0], v[1], v[2], v[3]};
    float ls = v[0] + v[1] + v[2] + v[3];
    #pragma unroll
    for (int off = 32; off >= 1; off >>= 1) ls += __shfl_down(ls, off, 64);
    if ((t & 63) == 0) sbuf[t >> 6] = ls;
    __syncthreads();
    float mean = (sbuf[0] + sbuf[1] + sbuf[2] + sbuf[3]) * (1.0f / D_);
    __syncthreads();
    float lv = 0.f;
    #pragma unroll
    for (int i = 0; i < 4; i++) { float d = v[i] - mean; lv += d * d; }
    #pragma unroll
    for (int off = 32; off >= 1; off >>= 1) lv += __shfl_down(lv, off, 64);
    if ((t & 63) == 0) sbuf[t >> 6] = lv;
    __syncthreads();
    float var = (sbuf[0] + sbuf[1] + sbuf[2] + sbuf[3]) * (1.0f / D_);
    float r = rsqrtf(var + 1e-5f);
    unsigned short* orow = lnout + (long long)row * D_;
    #pragma unroll
    for (int i = 0; i < 4; i++) {
        int c = t * 4 + i;
        orow[c] = f2b((v[i] - mean) * r * g3[c] + b3[c]);
    }
}

// ---------------------------------------------------------------- km row L2-normalize (bf16 in-place)
__global__ __launch_bounds__(256) void rownorm_b16(unsigned short* __restrict__ a)
{
    __shared__ float sbuf[4];
    int row = blockIdx.x;
    int t = threadIdx.x;
    unsigned short* ar = a + (long long)row * D_;
    ushort4 xv = *(const ushort4*)(ar + t * 4);
    float v0 = b2f(xv.x), v1 = b2f(xv.y), v2 = b2f(xv.z), v3 = b2f(xv.w);
    float ls = v0 * v0 + v1 * v1 + v2 * v2 + v3 * v3;
    #pragma unroll
    for (int off = 32; off >= 1; off >>= 1) ls += __shfl_down(ls, off, 64);
    if ((t & 63) == 0) sbuf[t >> 6] = ls;
    __syncthreads();
    float ss = sbuf[0] + sbuf[1] + sbuf[2] + sbuf[3];
    float sc = rsqrtf(ss + 1e-6f);
    ushort4 ov;
    ov.x = f2b(v0 * sc); ov.y = f2b(v1 * sc); ov.z = f2b(v2 * sc); ov.w = f2b(v3 * sc);
    *(ushort4*)(ar + t * 4) = ov;
}

// ---------------------------------------------------------------- transposes
// out row for input col c = (c>>4)*grpMul + (c&15) + rowAdd.
__global__ __launch_bounds__(256) void transpose_f32_b16(
    const float* __restrict__ in, unsigned short* __restrict__ out,
    int R, int Cc, long long izs, long long ozs, int grpMul, int rowAdd)
{
    __shared__ float tile[32][33];
    int z = blockIdx.z;
    const float* ib = in + (long long)z * izs;
    unsigned short* ob = out + (long long)z * ozs;
    int c0 = blockIdx.x * 32, r0 = blockIdx.y * 32;
    int tx = threadIdx.x & 31, ty = threadIdx.x >> 5;
    #pragma unroll
    for (int i = 0; i < 32; i += 8)
        tile[ty + i][tx] = ib[(long long)(r0 + ty + i) * Cc + c0 + tx];
    __syncthreads();
    #pragma unroll
    for (int i = 0; i < 32; i += 8) {
        int c = c0 + ty + i;
        long long orow = (long long)(c >> 4) * grpMul + (c & 15) + rowAdd;
        ob[orow * R + r0 + tx] = f2b(tile[tx][ty + i]);
    }
}

__global__ __launch_bounds__(256) void transpose_b16_b16(
    const unsigned short* __restrict__ in, unsigned short* __restrict__ out,
    int R, int Cc, long long izs, long long ozs)
{
    __shared__ unsigned short tile[32][33];
    int z = blockIdx.z;
    const unsigned short* ib = in + (long long)z * izs;
    unsigned short* ob = out + (long long)z * ozs;
    int c0 = blockIdx.x * 32, r0 = blockIdx.y * 32;
    int tx = threadIdx.x & 31, ty = threadIdx.x >> 5;
    #pragma unroll
    for (int i = 0; i < 32; i += 8)
        tile[ty + i][tx] = ib[(long long)(r0 + ty + i) * Cc + c0 + tx];
    __syncthreads();
    #pragma unroll
    for (int i = 0; i < 32; i += 8)
        ob[(long long)(c0 + ty + i) * R + r0 + tx] = tile[tx][ty + i];
}

// bffI[(i>>4)*32 + (i&15)] = gate bias; +16 = up bias (16-col pair interleave)
__global__ __launch_bounds__(256) void interleave16(
    const float* __restrict__ a, const float* __restrict__ b, float* __restrict__ o, int n)
{
    int i = blockIdx.x * 256 + threadIdx.x;
    if (i < n) {
        int r = ((i >> 4) << 5) + (i & 15);
        o[r] = a[i];
        o[r + 16] = b[i];
    }
}

// ---------------------------------------------------------------- 256x256 8-phase GEMM (m201-style)
// 512 thr = 8 waves (2x4). Iteration = 2 K-tiles (BK=64, fixed dbufs 0/1), 8 phases.
// Phase = { ds_reads (0/4/8/12) ; stage 2x64-row units into just-freed LDS ; barrier ;
//           lgkmcnt(0) ; setprio(1) ; 16 MFMA (one C-quadrant) ; setprio(0) ; barrier }.
// vmcnt(6) at end of phases 4 and 8 only (counted: 3 stage-pairs in flight).
// Both-sides (row&7) XOR swizzle. K must be a multiple of 128.
// MODE 0: N 16-col-interleaved gate/up pairs -> bf16 silu(gate)*up at [M][N/2].
// MODE 1: col-split (shift 10) bf16 out with optional bias (qkv fusion).
template<int MODE>
__global__ __launch_bounds__(512, 2) void gemm256(
    const unsigned short* __restrict__ A, const unsigned short* __restrict__ BT,
    const float* __restrict__ bias, unsigned short* __restrict__ outB,
    int K, int N, int Mrows)
{
    __shared__ short LA[2][256 * 64];
    __shared__ short LB[2][256 * 64];
    int row0 = blockIdx.y * 256, col0 = blockIdx.x * 256;
    int t = threadIdx.x;
    int wave = t >> 6, lane = t & 63;
    int wr = wave >> 2, wc = wave & 3;
    int quad = lane >> 4, lo = lane & 15;

    // one async_cp16 per thread = one 64-row unit u (rows u*64..u*64+63) of A or B
    auto stA = [&](int d, int tile, int u) {
        int c = u * 512 + t;
        int r = c >> 3, s = c & 7;
        int sc = s ^ (r & 7);
        async_cp16(A + (long long)(row0 + r) * K + tile * 64 + sc * 8,
                   &LA[d][(u * 512 + wave * 64) * 8]);
    };
    auto stB = [&](int d, int tile, int u) {
        int c = u * 512 + t;
        int r = c >> 3, s = c & 7;
        int sc = s ^ (r & 7);
        async_cp16(BT + (long long)(col0 + r) * K + tile * 64 + sc * 8,
                   &LB[d][(u * 512 + wave * 64) * 8]);
    };

    floatx4 acc[8][4];
    #pragma unroll
    for (int m = 0; m < 8; m++)
        #pragma unroll
        for (int n = 0; n < 4; n++) acc[m][n] = (floatx4){0.f, 0.f, 0.f, 0.f};

    // prologue: tile0 full (8 units), tile1 minus B u2,u3 (6 units) = 14 cp16
    stA(0, 0, 0); stA(0, 0, 1); stA(0, 0, 2); stA(0, 0, 3);
    stB(0, 0, 0); stB(0, 0, 1); stB(0, 0, 2); stB(0, 0, 3);
    stA(1, 1, 0); stA(1, 1, 1); stA(1, 1, 2); stA(1, 1, 3);
    stB(1, 1, 0); stB(1, 1, 1);
    wait_vm6();                          // tile0 landed (8 oldest of 14)
    __builtin_amdgcn_s_barrier();

    const int NI = K >> 7;               // 2 K-tiles per iteration
    short8 afA[4][2], afB[4][2], bf[4][2];
    for (int i = 0; i < NI; ++i) {
        const int t1 = 2 * i + 1, n2 = 2 * i + 2, n3 = 2 * i + 3;
        const bool pf = (i + 1 < NI);

        #pragma unroll
        for (int d = 0; d < 2; d++) {
            // ======== tile 2i+d from dbuf d, 4 phases ========
            // --- phA (ph1/ph5): reads afA(8) + bf n0-1 (4)
            #pragma unroll
            for (int m = 0; m < 4; m++)
                #pragma unroll
                for (int ks = 0; ks < 2; ks++) {
                    int row = wr * 128 + m * 16 + lo;
                    afA[m][ks] = *(const short8*)&LA[d][row * 64 + ((ks * 4 + quad) ^ (row & 7)) * 8];
                }
            #pragma unroll
            for (int n = 0; n < 2; n++)
                #pragma unroll
                for (int ks = 0; ks < 2; ks++) {
                    int row = wc * 64 + n * 16 + lo;
                    bf[n][ks] = *(const short8*)&LB[d][row * 64 + ((ks * 4 + quad) ^ (row & 7)) * 8];
                }
            SBAR();
            if (d == 0) { stB(1, t1, 2); stB(1, t1, 3); }          // finish tile 2i+1
            else if (pf) { stB(0, n2, 2); stB(0, n2, 3); }         // finish tile 2i+2
            wait_lgkm8();
            __builtin_amdgcn_s_barrier();
            wait_lgkm0(); SBAR();
            __builtin_amdgcn_s_setprio(1);
            #pragma unroll
            for (int m = 0; m < 4; m++)
                #pragma unroll
                for (int n = 0; n < 2; n++)
                    #pragma unroll
                    for (int ks = 0; ks < 2; ks++)
                        acc[m][n] = __builtin_amdgcn_mfma_f32_16x16x32_bf16(afA[m][ks], bf[n][ks], acc[m][n], 0, 0, 0);
            __builtin_amdgcn_s_setprio(0); SBAR();
            __builtin_amdgcn_s_barrier();

            // --- phB (ph2/ph6): reads bf n2-3 (4)
            #pragma unroll
            for (int n = 2; n < 4; n++)
                #pragma unroll
                for (int ks = 0; ks < 2; ks++) {
                    int row = wc * 64 + n * 16 + lo;
                    bf[n][ks] = *(const short8*)&LB[d][row * 64 + ((ks * 4 + quad) ^ (row & 7)) * 8];
                }
            SBAR();
            if (pf) { if (d == 0) { stA(0, n2, 0); stA(0, n2, 2); } else { stA(1, n3, 0); stA(1, n3, 2); } }
            __builtin_amdgcn_s_barrier();
            wait_lgkm0(); SBAR();
            __builtin_amdgcn_s_setprio(1);
            #pragma unroll
            for (int m = 0; m < 4; m++)
                #pragma unroll
                for (int n = 2; n < 4; n++)
                    #pragma unroll
                    for (int ks = 0; ks < 2; ks++)
                        acc[m][n] = __builtin_amdgcn_mfma_f32_16x16x32_bf16(afA[m][ks], bf[n][ks], acc[m][n], 0, 0, 0);
            __builtin_amdgcn_s_setprio(0); SBAR();
            __builtin_amdgcn_s_barrier();

            // --- phC (ph3/ph7): reads afB (8)
            #pragma unroll
            for (int m = 0; m < 4; m++)
                #pragma unroll
                for (int ks = 0; ks < 2; ks++) {
                    int row = wr * 128 + 64 + m * 16 + lo;
                    afB[m][ks] = *(const short8*)&LA[d][row * 64 + ((ks * 4 + quad) ^ (row & 7)) * 8];
                }
            SBAR();
            if (pf) { if (d == 0) { stB(0, n2, 0); stB(0, n2, 1); } else { stB(1, n3, 0); stB(1, n3, 1); } }
            __builtin_amdgcn_s_barrier();
            wait_lgkm0(); SBAR();
            __builtin_amdgcn_s_setprio(1);
            #pragma unroll
            for (int m = 0; m < 4; m++)
                #pragma unroll
                for (int n = 0; n < 2; n++)
                    #pragma unroll
                    for (int ks = 0; ks < 2; ks++)
                        acc[4 + m][n] = __builtin_amdgcn_mfma_f32_16x16x32_bf16(afB[m][ks], bf[n][ks], acc[4 + m][n], 0, 0, 0);
            __builtin_amdgcn_s_setprio(0); SBAR();
            __builtin_amdgcn_s_barrier();

            // --- phD (ph4/ph8): no reads
            if (pf) { if (d == 0) { stA(0, n2, 1); stA(0, n2, 3); } else { stA(1, n3, 1); stA(1, n3, 3); } }
            __builtin_amdgcn_s_barrier();
            __builtin_amdgcn_s_setprio(1);
            #pragma unroll
            for (int m = 0; m < 4; m++)
                #pragma unroll
                for (int n = 2; n < 4; n++)
                    #pragma unroll
                    for (int ks = 0; ks < 2; ks++)
                        acc[4 + m][n] = __builtin_amdgcn_mfma_f32_16x16x32_bf16(afB[m][ks], bf[n][ks], acc[4 + m][n], 0, 0, 0);
            __builtin_amdgcn_s_setprio(0); SBAR();
            // counted drain: ph4 protects tile 2i+1 (its last units staged at ph1);
            // ph8 protects tile 2i+2 (last units staged at ph5).
            if (d == 0) { if (i == NI - 1) wait_vm0(); else wait_vm6(); }
            else if (i < NI - 1) wait_vm6();
            __builtin_amdgcn_s_barrier();
        }
    }

    if (MODE == 0) {
        #pragma unroll
        for (int m = 0; m < 8; m++)
            #pragma unroll
            for (int n = 0; n < 4; n += 2) {
                int cg = col0 + wc * 64 + n * 16 + lo;
                float bg = bias ? bias[cg] : 0.f;
                float bu = bias ? bias[cg + 16] : 0.f;
                int fc = ((cg >> 5) << 4) + (cg & 15);
                #pragma unroll
                for (int r = 0; r < 4; r++) {
                    int row = row0 + wr * 128 + m * 16 + quad * 4 + r;
                    float vg = acc[m][n][r] + bg;
                    float vu = acc[m][n + 1][r] + bu;
                    float sg = vg / (1.0f + __expf(-vg));
                    outB[(long long)row * (N >> 1) + fc] = f2b(sg * vu);
                }
            }
    } else {
        #pragma unroll
        for (int m = 0; m < 8; m++)
            #pragma unroll
            for (int n = 0; n < 4; n++) {
                int col = col0 + wc * 64 + n * 16 + lo;
                float bv = bias ? bias[col] : 0.f;
                #pragma unroll
                for (int r = 0; r < 4; r++) {
                    int row = row0 + wr * 128 + m * 16 + quad * 4 + r;
                    long long idx = (((long long)(col >> 10) * Mrows + row) << 10) + (col & 1023);
                    outB[idx] = f2b(acc[m][n][r] + bv);
                }
            }
    }
}

// ---------------------------------------------------------------- 128x128 deep-pipeline core
// 256 thr = 4 waves (2x2), BK=64, 64 KiB LDS dbuf (2 blocks/CU), counted vmcnt(8).
__device__ __forceinline__ void core128(
    const unsigned short* __restrict__ Ab, int lda,
    const unsigned short* __restrict__ Bb, int ldb,
    int row0, int col0, int K,
    short (&L)[2][2][128 * 64], floatx4 (&acc)[4][4])
{
    int t = threadIdx.x;
    int wave = t >> 6, lane = t & 63;
    int wr = wave >> 1, wc = wave & 1;
    int quad = lane >> 4, lo = lane & 15;

    const unsigned short* gA = Ab + (long long)row0 * lda;
    const unsigned short* gB = Bb + (long long)col0 * ldb;

    auto STAGE = [&](int buf, int kt) {
        #pragma unroll
        for (int nn = 0; nn < 4; nn++) {
            int c = nn * 256 + t;
            int r = c >> 3, s = c & 7;
            int sc = s ^ (r & 7);
            async_cp16(gA + (long long)r * lda + kt * 64 + sc * 8,
                       &L[buf][0][(nn * 256 + wave * 64) * 8]);
        }
        #pragma unroll
        for (int nn = 0; nn < 4; nn++) {
            int c = nn * 256 + t;
            int r = c >> 3, s = c & 7;
            int sc = s ^ (r & 7);
            async_cp16(gB + (long long)r * ldb + kt * 64 + sc * 8,
                       &L[buf][1][(nn * 256 + wave * 64) * 8]);
        }
    };

    #pragma unroll
    for (int m = 0; m < 4; m++)
        #pragma unroll
        for (int n = 0; n < 4; n++) acc[m][n] = (floatx4){0.f, 0.f, 0.f, 0.f};

    STAGE(0, 0);
    STAGE(1, 1);

    const int NT = K >> 6;
    for (int kt = 0; kt < NT; ++kt) {
        int cur = kt & 1;
        if (kt == NT - 1) wait_vm0(); else wait_vm8();
        __builtin_amdgcn_s_barrier();
        SBAR();

        short8 af[4][2], bf[4][2];
        #pragma unroll
        for (int m = 0; m < 4; m++)
            #pragma unroll
            for (int ks = 0; ks < 2; ks++) {
                int row = wr * 64 + m * 16 + lo;
                int ch = (ks * 4 + quad) ^ (row & 7);
                af[m][ks] = *(const short8*)&L[cur][0][row * 64 + ch * 8];
            }
        #pragma unroll
        for (int n = 0; n < 4; n++)
            #pragma unroll
            for (int ks = 0; ks < 2; ks++) {
                int row = wc * 64 + n * 16 + lo;
                int ch = (ks * 4 + quad) ^ (row & 7);
                bf[n][ks] = *(const short8*)&L[cur][1][row * 64 + ch * 8];
            }
        #pragma unroll
        for (int m = 0; m < 4; m++)
            #pragma unroll
            for (int n = 0; n < 4; n++)
                acc[m][n] = __builtin_amdgcn_mfma_f32_16x16x32_bf16(af[m][0], bf[n][0], acc[m][n], 0, 0, 0);

        wait_lgkm0();
        SBAR();
        __builtin_amdgcn_s_barrier();
        SBAR();
        if (kt + 2 < NT) STAGE(cur, kt + 2);

        #pragma unroll
        for (int m = 0; m < 4; m++)
            #pragma unroll
            for (int n = 0; n < 4; n++)
                acc[m][n] = __builtin_amdgcn_mfma_f32_16x16x32_bf16(af[m][1], bf[n][1], acc[m][n], 0, 0, 0);
    }
}

// z-batched 128x128 pipelined GEMM. z -> (zlo = z & mask, zhi = z >> zLoBits).
// RESID=0: outF fp32 (z strides) and/or outB bf16 (z strides), bias[z*biasZs + col].
// RESID=1: outF[bb*oBS + s*N + col] = acc + bias + resid[same] (batch-mapped rows).
template<int RESID>
__global__ __launch_bounds__(256, 2) void gemm128p(
    const unsigned short* __restrict__ A, long long AzsLo, long long AzsHi, int zLoBits, int lda,
    const unsigned short* __restrict__ BT, long long BzsLo, long long BzsHi, int ldb,
    const float* __restrict__ bias, long long biasZs,
    float* __restrict__ outF, long long OFzsLo, long long OFzsHi,
    unsigned short* __restrict__ outB, long long OBzsLo, long long OBzsHi,
    int K, int N, int rowsPB, long long oBS, const float* __restrict__ resid)
{
    __shared__ short L[2][2][128 * 64];
    int z = blockIdx.z;
    long long zlo = z & ((1 << zLoBits) - 1);
    long long zhi = z >> zLoBits;
    int row0 = blockIdx.y * 128, col0 = blockIdx.x * 128;
    floatx4 acc[4][4];
    core128(A + zlo * AzsLo + zhi * AzsHi, lda,
            BT + zlo * BzsLo + zhi * BzsHi, ldb, row0, col0, K, L, acc);

    int t = threadIdx.x, wave = t >> 6, lane = t & 63;
    int wr = wave >> 1, wc = wave & 1;
    int quad = lane >> 4, lo = lane & 15;
    long long oF0 = zlo * OFzsLo + zhi * OFzsHi;
    long long oB0 = zlo * OBzsLo + zhi * OBzsHi;
    #pragma unroll
    for (int m = 0; m < 4; m++)
        #pragma unroll
        for (int n = 0; n < 4; n++) {
            int col = col0 + wc * 64 + n * 16 + lo;
            float bv = bias ? bias[(long long)z * biasZs + col] : 0.f;
            #pragma unroll
            for (int r = 0; r < 4; r++) {
                int row = row0 + wr * 64 + m * 16 + quad * 4 + r;
                float v = acc[m][n][r] + bv;
                if (RESID) {
                    int bb = row / rowsPB, s = row - bb * rowsPB;
                    long long oi = (long long)bb * oBS + (long long)s * N + col;
                    outF[oi] = v + resid[oi];
                } else {
                    long long idx = (long long)row * N + col;
                    if (outF) outF[oF0 + idx] = v;
                    if (outB) outB[oB0 + idx] = f2b(v);
                }
            }
        }
}

// serial chunk update: gradT = MTbPrev @ KK - KVT; ST = eta*ST - theta*gradT;
// MT = (1-alpha)*MT + ST; MTbNext = bf16(MT). z = batch (4).
__global__ __launch_bounds__(256, 2) void gemm128_mupd(
    const unsigned short* __restrict__ Ap, const unsigned short* __restrict__ Bp,
    const unsigned short* __restrict__ KVT,
    float* __restrict__ ST, float* __restrict__ MT, unsigned short* __restrict__ MTbN,
    const float* __restrict__ lr, const float* __restrict__ mom, const float* __restrict__ fg)
{
    __shared__ short L[2][2][128 * 64];
    int z = blockIdx.z;
    long long zb = (long long)z * D_ * D_;
    int row0 = blockIdx.y * 128, col0 = blockIdx.x * 128;
    floatx4 acc[4][4];
    core128(Ap + zb, D_, Bp + zb, D_, row0, col0, D_, L, acc);

    int t = threadIdx.x, wave = t >> 6, lane = t & 63;
    int wr = wave >> 1, wc = wave & 1;
    int quad = lane >> 4, lo = lane & 15;
    float theta = sigmoidf_(lr[0]) * (1.0f / C_);
    float eta   = sigmoidf_(mom[0]);
    float alpha = sigmoidf_(fg[0]);
    #pragma unroll
    for (int m = 0; m < 4; m++)
        #pragma unroll
        for (int n = 0; n < 4; n++) {
            int col = col0 + wc * 64 + n * 16 + lo;
            #pragma unroll
            for (int r = 0; r < 4; r++) {
                int row = row0 + wr * 64 + m * 16 + quad * 4 + r;
                long long idx = zb + (long long)row * D_ + col;
                float gv = acc[m][n][r] - b2f(KVT[idx]);
                float st = eta * ST[idx] - theta * gv;
                ST[idx] = st;
                float mm = (1.0f - alpha) * MT[idx] + st;
                MT[idx] = mm;
                MTbN[idx] = f2b(mm);
            }
        }
}

// ---------------------------------------------------------------- MFMA flash attention (group-batched)
__global__ __launch_bounds__(256) void attn_mfma(
    const unsigned short* __restrict__ qh, const unsigned short* __restrict__ kh,
    const unsigned short* __restrict__ vh,
    const float* __restrict__ pk, const float* __restrict__ pv,
    unsigned short* __restrict__ ao, int GC)
{
    __shared__ __align__(16) short Ks[64][KP_];
    __shared__ __align__(16) short Vs[64][KP_];
    __shared__ __align__(16) short Ps[4][16][KP_];
    int qb = blockIdx.x, h = blockIdx.y, b = blockIdx.z;
    int q0 = qb * 64;
    int kbase = q0 & ~(C_ - 1);
    int t = threadIdx.x;
    int wave = t >> 6, lane = t & 63;
    int quad = lane >> 4, lo = lane & 15;

    short8 qf[2];
    {
        const unsigned short* qp = qh + (long long)(b * GC + q0 + wave * 16 + lo) * (H_ * DH_)
                                   + h * DH_ + quad * 8;
        qf[0] = *(const short8*)qp;
        qf[1] = *(const short8*)(qp + 32);
    }
    floatx4 o4[4];
    #pragma unroll
    for (int dt = 0; dt < 4; dt++) o4[dt] = (floatx4){0.f, 0.f, 0.f, 0.f};
    float m[4], l[4];
    #pragma unroll
    for (int r = 0; r < 4; r++) { m[r] = -1e30f; l[r] = 0.f; }
    {
        short* pz = &Ps[wave][lo][16 + quad * 4];
        pz[0] = 0; pz[1] = 0; pz[2] = 0; pz[3] = 0;
    }

    int ktmax = ((q0 - kbase) >> 6) + 1;
    for (int kt = 0; kt <= ktmax; kt++) {
        __syncthreads();
        if (kt == 0) {
            int key = t >> 4, d4 = (t & 15) * 4;
            float4 kv4 = *(const float4*)(pk + ((long long)key * H_ + h) * DH_ + d4);
            Ks[key][d4 + 0] = f2b(kv4.x); Ks[key][d4 + 1] = f2b(kv4.y);
            Ks[key][d4 + 2] = f2b(kv4.z); Ks[key][d4 + 3] = f2b(kv4.w);
            float4 vv4 = *(const float4*)(pv + ((long long)key * H_ + h) * DH_ + d4);
            Vs[d4 + 0][key] = f2b(vv4.x); Vs[d4 + 1][key] = f2b(vv4.y);
            Vs[d4 + 2][key] = f2b(vv4.z); Vs[d4 + 3][key] = f2b(vv4.w);
            int dz = t >> 2, kz = 16 + (t & 3) * 4;
            Vs[dz][kz + 0] = 0; Vs[dz][kz + 1] = 0;
            Vs[dz][kz + 2] = 0; Vs[dz][kz + 3] = 0;
        } else {
            int tok0 = kbase + (kt - 1) * 64;
            {
                int key = t >> 2, dblk = (t & 3) * 16;
                const unsigned short* kp2 = kh + (long long)(b * GC + tok0 + key) * (H_ * DH_)
                                            + h * DH_ + dblk;
                *(short8*)&Ks[key][dblk]     = *(const short8*)kp2;
                *(short8*)&Ks[key][dblk + 8] = *(const short8*)(kp2 + 8);
            }
            {
                int kp = t & 31, dg = t >> 5;
                const unsigned short* vp0 = vh + (long long)(b * GC + tok0 + 2 * kp) * (H_ * DH_)
                                            + h * DH_ + dg * 8;
                short8 v0 = *(const short8*)vp0;
                short8 v1 = *(const short8*)(vp0 + H_ * DH_);
                #pragma unroll
                for (int j = 0; j < 8; j++) {
                    unsigned int pk2 = ((unsigned int)(unsigned short)v1[j] << 16)
                                     | (unsigned short)v0[j];
                    *(unsigned int*)&Vs[dg * 8 + j][2 * kp] = pk2;
                }
            }
        }
        __syncthreads();

        int ntiles = (kt == 0) ? 1 : 4;
        floatx4 s4[4];
        #pragma unroll
        for (int nt = 0; nt < 4; nt++) {
            if (nt >= ntiles) break;
            s4[nt] = (floatx4){0.f, 0.f, 0.f, 0.f};
            #pragma unroll
            for (int ks = 0; ks < 2; ks++) {
                short8 bfr = *(const short8*)&Ks[nt * 16 + lo][ks * 32 + quad * 8];
                s4[nt] = __builtin_amdgcn_mfma_f32_16x16x32_bf16(qf[ks], bfr, s4[nt], 0, 0, 0);
            }
        }
        bool diag = (kt == ktmax);
        int key0 = kbase + (kt - 1) * 64;
        #pragma unroll
        for (int nt = 0; nt < 4; nt++) {
            if (nt >= ntiles) break;
            #pragma unroll
            for (int r = 0; r < 4; r++) {
                float v = s4[nt][r] * 0.125f;
                if (diag) {
                    int kg = key0 + nt * 16 + lo;
                    int qq = q0 + wave * 16 + quad * 4 + r;
                    if (kg > qq) v = -1e30f;
                }
                s4[nt][r] = v;
            }
        }
        float alpha[4];
        #pragma unroll
        for (int r = 0; r < 4; r++) {
            float tm = s4[0][r];
            #pragma unroll
            for (int nt = 1; nt < 4; nt++) { if (nt >= ntiles) break; tm = fmaxf(tm, s4[nt][r]); }
            #pragma unroll
            for (int msk = 1; msk <= 8; msk <<= 1) tm = fmaxf(tm, __shfl_xor(tm, msk, 64));
            float mn = fmaxf(m[r], tm);
            alpha[r] = __expf(m[r] - mn);
            float sum = 0.f;
            #pragma unroll
            for (int nt = 0; nt < 4; nt++) {
                if (nt >= ntiles) break;
                float p = __expf(s4[nt][r] - mn);
                sum += p;
                Ps[wave][quad * 4 + r][nt * 16 + lo] = f2b(p);
            }
            #pragma unroll
            for (int msk = 1; msk <= 8; msk <<= 1) sum += __shfl_xor(sum, msk, 64);
            l[r] = l[r] * alpha[r] + sum;
            m[r] = mn;
        }
        #pragma unroll
        for (int dt = 0; dt < 4; dt++)
            #pragma unroll
            for (int r = 0; r < 4; r++) o4[dt][r] *= alpha[r];
        __syncthreads();
        int ksteps = (kt == 0) ? 1 : 2;
        #pragma unroll
        for (int ks = 0; ks < 2; ks++) {
            if (ks >= ksteps) break;
            short8 afr = *(const short8*)&Ps[wave][lo][ks * 32 + quad * 8];
            #pragma unroll
            for (int dt = 0; dt < 4; dt++) {
                short8 bfr = *(const short8*)&Vs[dt * 16 + lo][ks * 32 + quad * 8];
                o4[dt] = __builtin_amdgcn_mfma_f32_16x16x32_bf16(afr, bfr, o4[dt], 0, 0, 0);
            }
        }
    }
    #pragma unroll
    for (int r = 0; r < 4; r++) {
        float inv = 1.0f / l[r];
        int q = q0 + wave * 16 + quad * 4 + r;
        unsigned short* aop = ao + (long long)(b * GC + q) * (H_ * DH_) + h * DH_ + lo;
        #pragma unroll
        for (int dt = 0; dt < 4; dt++) aop[dt * 16] = f2b(o4[dt][r] * inv);
    }
}

// ---------------------------------------------------------------- launch
extern "C" void kernel_launch(void* const* d_in, const int* in_sizes, int n_in,
                              void* d_out, int out_size, void* d_ws, size_t ws_size,
                              hipStream_t stream)
{
    const float* x     = (const float*)d_in[0];
    const float* g1    = (const float*)d_in[1];
    const float* b1    = (const float*)d_in[2];
    const float* g2    = (const float*)d_in[3];
    const float* b2    = (const float*)d_in[4];
    const float* g3    = (const float*)d_in[5];
    const float* b3    = (const float*)d_in[6];
    const float* Wqm   = (const float*)d_in[7];
    const float* Wkm   = (const float*)d_in[8];
    const float* Wvm   = (const float*)d_in[9];
    const float* lr    = (const float*)d_in[10];
    const float* mom   = (const float*)d_in[11];
    const float* fg    = (const float*)d_in[12];
    const float* Wq    = (const float*)d_in[13];
    const float* bq    = (const float*)d_in[14];
    const float* Wk    = (const float*)d_in[15];
    const float* bk    = (const float*)d_in[16];
    const float* Wv    = (const float*)d_in[17];
    const float* bv    = (const float*)d_in[18];
    const float* Wo    = (const float*)d_in[19];
    const float* bo    = (const float*)d_in[20];
    const float* pk    = (const float*)d_in[21];
    const float* pv    = (const float*)d_in[22];
    const float* Wg    = (const float*)d_in[23];
    const float* bg    = (const float*)d_in[24];
    const float* Wgate = (const float*)d_in[25];
    const float* bgate = (const float*)d_in[26];
    const float* Wup   = (const float*)d_in[27];
    const float* bup   = (const float*)d_in[28];
    const float* Wdown = (const float*)d_in[29];
    const float* bdown = (const float*)d_in[30];
    float* out = (float*)d_out;

    const long long MiB = 1024LL * 1024LL;
    const long long D2 = (long long)D_ * D_;
    char* w = (char*)d_ws;

    // ---- group size: total = 82 + 60*G MiB (G in {8,4,2,1})
    int G = 8;
    while (G > 1 && (size_t)((82 + 60 * G) * MiB) > ws_size) G >>= 1;
    const int GC = G * C_;
    const int NG = NC_ / G;
    const int RG = B_ * GC;
    const int RING = G + 1;
    int gcShift = 0; while ((1 << gcShift) < GC) gcShift++;
    const long long GiM = (long long)G * MiB;

    // ---- fixed region
    float* MT  = (float*)(w + 0 * MiB);                          // 16
    float* ST  = (float*)(w + 16 * MiB);                         // 16
    unsigned short* MTb = (unsigned short*)(w + 32 * MiB);       // 8*(G+1) ring of bf16 M^T
    char* wt = w + (32 + 8 * (long long)RING) * MiB;
    unsigned short* WqkvmT = (unsigned short*)(wt + 0 * MiB);    // 6
    unsigned short* WqkvhT = (unsigned short*)(wt + 6 * MiB);    // 6
    unsigned short* WoT    = (unsigned short*)(wt + 12 * MiB);   // 2
    unsigned short* WgT    = (unsigned short*)(wt + 14 * MiB);   // 2
    unsigned short* WffT   = (unsigned short*)(wt + 16 * MiB);   // 16 [8192][1024] 16-col-pair interleave
    unsigned short* WdownT = (unsigned short*)(wt + 32 * MiB);   // 8
    float* bqkvh = (float*)(wt + 40 * MiB);                      // 12 KB
    float* bffI  = (float*)(wt + 40 * MiB + 65536);              // 32 KB interleaved
    float* bog   = (float*)(wt + 40 * MiB + 131072);             // 8 KB
    char* gbase = wt + 41 * MiB;

    // ---- group region (G·MiB units)
    unsigned short* QKVm   = (unsigned short*)(gbase);                 // qm|km|vm, later qh|kh|vh
    unsigned short* kmTG   = (unsigned short*)(gbase + 12 * GiM);      // [b][D][GC]; later Hao
    unsigned short* vmTG   = (unsigned short*)(gbase + 16 * GiM);      // [b][D][GC]
    unsigned short* KK     = (unsigned short*)(gbase + 20 * GiM);      // [j][b][D][D] bf16
    unsigned short* KVT    = (unsigned short*)(gbase + 28 * GiM);      // [j][b][D][D] bf16
    float* mctx32          = (float*)(gbase + 36 * GiM);
    unsigned short* mctx16 = (unsigned short*)(gbase + 44 * GiM);
    unsigned short* LNout  = (unsigned short*)(gbase + 48 * GiM);
    // overlays (dead-by-then regions)
    unsigned short* Hao = kmTG;
    float* aoW = (float*)KK;
    float* gG  = (float*)KVT;
    unsigned short* G0 = QKVm;

    hipMemsetAsync(d_ws, 0, (size_t)((32 + 8 * (long long)RING) * MiB), stream);  // MT, ST, MTb ring

    // concat / interleave biases
    hipMemcpyAsync(bqkvh,        bq, 4096, hipMemcpyDeviceToDevice, stream);
    hipMemcpyAsync(bqkvh + 1024, bk, 4096, hipMemcpyDeviceToDevice, stream);
    hipMemcpyAsync(bqkvh + 2048, bv, 4096, hipMemcpyDeviceToDevice, stream);
    hipMemcpyAsync(bog,          bo, 4096, hipMemcpyDeviceToDevice, stream);
    hipMemcpyAsync(bog + 1024,   bg, 4096, hipMemcpyDeviceToDevice, stream);
    interleave16<<<16, 256, 0, stream>>>(bgate, bup, bffI, FF_);

    // weight transposes -> bf16 [N][K]; Wgate/Wup 16-col-pair interleaved into WffT
    transpose_f32_b16<<<dim3(32, 32, 1), 256, 0, stream>>>(Wqm, WqkvmT,           D_, D_, 0, 0, 16, 0);
    transpose_f32_b16<<<dim3(32, 32, 1), 256, 0, stream>>>(Wkm, WqkvmT + 1048576, D_, D_, 0, 0, 16, 0);
    transpose_f32_b16<<<dim3(32, 32, 1), 256, 0, stream>>>(Wvm, WqkvmT + 2097152, D_, D_, 0, 0, 16, 0);
    transpose_f32_b16<<<dim3(32, 32, 1), 256, 0, stream>>>(Wq,  WqkvhT,           D_, D_, 0, 0, 16, 0);
    transpose_f32_b16<<<dim3(32, 32, 1), 256, 0, stream>>>(Wk,  WqkvhT + 1048576, D_, D_, 0, 0, 16, 0);
    transpose_f32_b16<<<dim3(32, 32, 1), 256, 0, stream>>>(Wv,  WqkvhT + 2097152, D_, D_, 0, 0, 16, 0);
    transpose_f32_b16<<<dim3(32, 32, 1), 256, 0, stream>>>(Wo,  WoT,              D_, D_, 0, 0, 16, 0);
    transpose_f32_b16<<<dim3(32, 32, 1), 256, 0, stream>>>(Wg,  WgT,              D_, D_, 0, 0, 16, 0);
    transpose_f32_b16<<<dim3(128, 32, 1), 256, 0, stream>>>(Wgate, WffT,          D_, FF_, 0, 0, 32, 0);
    transpose_f32_b16<<<dim3(128, 32, 1), 256, 0, stream>>>(Wup,   WffT,          D_, FF_, 0, 0, 32, 16);
    transpose_f32_b16<<<dim3(32, 128, 1), 256, 0, stream>>>(Wdown, WdownT,        FF_, D_, 0, 0, 16, 0);

    const long long xBS = (long long)S_ * D_;

    for (int g = 0; g < NG; g++) {
        const float* xg = x   + (long long)g * GC * D_;
        float* og       = out + (long long)g * GC * D_;
        int s0 = (g * G) % RING;

        // A) h1 = LN1(x) -> LNout
        ln_kernel<<<RG, 256, 0, stream>>>(xg, xBS, GC, nullptr, g1, b1, LNout);
        // B) qm|km|vm -> QKVm (col-split slots of [RG][1024])
        gemm256<1><<<dim3(12, RG / 256), 512, 0, stream>>>(LNout, WqkvmT, nullptr, QKVm, D_, 3072, RG);
        // C) km normalize; kmT, vmT -> [b][D][GC]
        rownorm_b16<<<RG, 256, 0, stream>>>(QKVm + (long long)RG * D_);
        transpose_b16_b16<<<dim3(32, GC / 32, 4), 256, 0, stream>>>(QKVm + (long long)RG * D_,
            kmTG, GC, D_, (long long)GC * D_, (long long)D_ * GC);
        transpose_b16_b16<<<dim3(32, GC / 32, 4), 256, 0, stream>>>(QKVm + 2LL * RG * D_,
            vmTG, GC, D_, (long long)GC * D_, (long long)D_ * GC);
        // D1) KK[j][b] = kmT_j . km_j  (zlo=b, zhi=j)
        gemm128p<0><<<dim3(8, 8, 4 * G), 256, 0, stream>>>(
            kmTG, (long long)D_ * GC, (long long)C_, 2, GC,
            kmTG, (long long)D_ * GC, (long long)C_, GC,
            nullptr, 0,
            nullptr, 0, 0,
            KK, D2, 4 * D2,
            C_, D_, 0, 0, nullptr);
        // D2) KVT[j][b] = vmT_j . km_j
        gemm128p<0><<<dim3(8, 8, 4 * G), 256, 0, stream>>>(
            vmTG, (long long)D_ * GC, (long long)C_, 2, GC,
            kmTG, (long long)D_ * GC, (long long)C_, GC,
            nullptr, 0,
            nullptr, 0, 0,
            KVT, D2, 4 * D2,
            C_, D_, 0, 0, nullptr);
        // D3) serial chain: one fused GEMM+update per chunk
        for (int j = 0; j < G; j++) {
            int sp = (s0 + j) % RING, sn = (s0 + j + 1) % RING;
            gemm128_mupd<<<dim3(8, 8, 4), 256, 0, stream>>>(
                MTb + (long long)sp * 4 * D2, KK + (long long)j * 4 * D2,
                KVT + (long long)j * 4 * D2, ST, MT, MTb + (long long)sn * 4 * D2,
                lr, mom, fg);
        }
        // D4) mem_ctx = qm_j @ M_{j-1}
        if (G <= 2) {
            long long stride = (G == 2) ? (((s0 + 1) % RING) - s0) : 0;
            gemm128p<0><<<dim3(8, 4, 4 * G), 256, 0, stream>>>(
                QKVm, (long long)GC * D_, (long long)C_ * D_, 2, D_,
                MTb + (long long)s0 * 4 * D2, D2, stride * 4 * D2, D_,
                nullptr, 0,
                mctx32, (long long)GC * D_, (long long)C_ * D_,
                mctx16, (long long)GC * D_, (long long)C_ * D_,
                D_, D_, 0, 0, nullptr);
        } else {
            for (int j = 0; j < G; j++) {
                int sp = (s0 + j) % RING;
                gemm128p<0><<<dim3(8, 4, 4), 256, 0, stream>>>(
                    QKVm + (long long)j * C_ * D_, (long long)GC * D_, 0, 2, D_,
                    MTb + (long long)sp * 4 * D2, D2, 0, D_,
                    nullptr, 0,
                    mctx32 + (long long)j * C_ * D_, (long long)GC * D_, 0,
                    mctx16 + (long long)j * C_ * D_, (long long)GC * D_, 0,
                    D_, D_, 0, 0, nullptr);
            }
        }
        // E) h2 = LN2(x + mem_ctx) -> LNout
        ln_kernel<<<RG, 256, 0, stream>>>(xg, xBS, GC, mctx32, g2, b2, LNout);
        // F) qh|kh|vh -> QKVm
        gemm256<1><<<dim3(12, RG / 256), 512, 0, stream>>>(LNout, WqkvhT, bqkvh, QKVm, D_, 3072, RG);
        // G) attention -> Hao
        attn_mfma<<<dim3(GC / 64, H_, B_), 256, 0, stream>>>(QKVm, QKVm + (long long)RG * D_,
            QKVm + 2LL * RG * D_, pk, pv, Hao, GC);
        // H+I) z=0: aoW = Hao@Wo+bo ; z=1: gG = mctx16@Wg+bg
        gemm128p<0><<<dim3(8, RG / 128, 2), 256, 0, stream>>>(
            Hao, (long long)(mctx16 - Hao), 0, 30, D_,
            WoT, (long long)(WgT - WoT), 0, D_,
            bog, 1024,
            aoW, (long long)(gG - aoW), 0,
            nullptr, 0, 0,
            D_, D_, 0, 0, nullptr);
        // J) fused gate-combine + LN3 -> og, LNout
        gate_ln_kernel<<<RG, 256, 0, stream>>>(xg, xBS, gcShift, gG, aoW, mctx32,
            g3, b3, og, LNout);
        // L) FFN gate|up 16-pair interleaved, fused silu*up -> G0 [RG][4096] bf16
        gemm256<0><<<dim3(32, RG / 256), 512, 0, stream>>>(LNout, WffT, bffI, G0, D_, 8192, 0);
        // N) out = o + prod @ Wdown + bdown
        gemm128p<1><<<dim3(8, RG / 128, 1), 256, 0, stream>>>(
            G0, 0, 0, 0, FF_,
            WdownT, 0, 0, FF_,
            bdown, 0,
            og, 0, 0,
            nullptr, 0, 0,
            FF_, D_, GC, xBS, og);
    }
}

// Round 8
// 1907.255 us; speedup vs baseline: 1.0370x; 1.0370x over previous
//
#include <hip/hip_runtime.h>
#include <hip/hip_bf16.h>
#include <math.h>

#define D_ 1024
#define C_ 512
#define H_ 16
#define DH_ 64
#define P_ 16
#define FF_ 4096
#define S_ 4096
#define B_ 4
#define NC_ 8
#define KP_ 72   // attn LDS pitch (shorts)

typedef __attribute__((ext_vector_type(8))) short short8;
typedef __attribute__((ext_vector_type(4))) float floatx4;

__device__ __forceinline__ float sigmoidf_(float x) { return 1.0f / (1.0f + __expf(-x)); }
__device__ __forceinline__ unsigned short f2b(float x) {
    __hip_bfloat16 h = __float2bfloat16(x);
    return __builtin_bit_cast(unsigned short, h);
}
__device__ __forceinline__ float b2f(unsigned short u) {
    __hip_bfloat16 h = __builtin_bit_cast(__hip_bfloat16, u);
    return __bfloat162float(h);
}
// async global->LDS 16B: LDS dst = wave-uniform base + lane*16
__device__ __forceinline__ void async_cp16(const unsigned short* g, short* l) {
    __builtin_amdgcn_global_load_lds(
        (const __attribute__((address_space(1))) void*)g,
        (__attribute__((address_space(3))) void*)l, 16, 0, 0);
}
__device__ __forceinline__ void wait_vm8()   { asm volatile("s_waitcnt vmcnt(8)" ::: "memory"); }
__device__ __forceinline__ void wait_vm0()   { asm volatile("s_waitcnt vmcnt(0)" ::: "memory"); }
__device__ __forceinline__ void wait_lgkm0() { asm volatile("s_waitcnt lgkmcnt(0)" ::: "memory"); }
#define SBAR() __builtin_amdgcn_sched_barrier(0)

// ---------------------------------------------------------------- LayerNorm (fp32 in, bf16 out)
__global__ __launch_bounds__(256) void ln_kernel(
    const float* __restrict__ x, long long xBatchStride, int rowsPerBatch,
    const float* __restrict__ add,
    const float* __restrict__ g, const float* __restrict__ beta,
    unsigned short* __restrict__ out)
{
    __shared__ float sbuf[4];
    int row = blockIdx.x;
    int bb = row / rowsPerBatch, s = row - bb * rowsPerBatch;
    const float* xr = x + (long long)bb * xBatchStride + (long long)s * D_;
    int t = threadIdx.x;
    float v[4];
    float4 xv = *(const float4*)(xr + t * 4);
    v[0] = xv.x; v[1] = xv.y; v[2] = xv.z; v[3] = xv.w;
    if (add) {
        float4 av = *(const float4*)(add + (long long)row * D_ + t * 4);
        v[0] += av.x; v[1] += av.y; v[2] += av.z; v[3] += av.w;
    }
    float ls = v[0] + v[1] + v[2] + v[3];
    #pragma unroll
    for (int off = 32; off >= 1; off >>= 1) ls += __shfl_down(ls, off, 64);
    if ((t & 63) == 0) sbuf[t >> 6] = ls;
    __syncthreads();
    float mean = (sbuf[0] + sbuf[1] + sbuf[2] + sbuf[3]) * (1.0f / D_);
    __syncthreads();
    float lv = 0.f;
    #pragma unroll
    for (int i = 0; i < 4; i++) { float d = v[i] - mean; lv += d * d; }
    #pragma unroll
    for (int off = 32; off >= 1; off >>= 1) lv += __shfl_down(lv, off, 64);
    if ((t & 63) == 0) sbuf[t >> 6] = lv;
    __syncthreads();
    float var = (sbuf[0] + sbuf[1] + sbuf[2] + sbuf[3]) * (1.0f / D_);
    float r = rsqrtf(var + 1e-5f);
    unsigned short* orow = out + (long long)row * D_;
    #pragma unroll
    for (int i = 0; i < 4; i++) {
        int c = t * 4 + i;
        orow[c] = f2b((v[i] - mean) * r * g[c] + beta[c]);
    }
}

// ---------------------------------------------------------------- fused gate-combine + LN3
__global__ __launch_bounds__(256) void gate_ln_kernel(
    const float* __restrict__ x, long long xBS, int gcShift,
    const float* __restrict__ gbuf, const float* __restrict__ aoW,
    const float* __restrict__ mctx,
    const float* __restrict__ g3, const float* __restrict__ b3,
    float* __restrict__ og, unsigned short* __restrict__ lnout)
{
    __shared__ float sbuf[4];
    int row = blockIdx.x;
    int bb = row >> gcShift, s = row & ((1 << gcShift) - 1);
    int t = threadIdx.x;
    long long fbase = (long long)row * D_ + t * 4;
    long long xbase = (long long)bb * xBS + (long long)s * D_ + t * 4;
    float4 xv = *(const float4*)(x + xbase);
    float4 gv = *(const float4*)(gbuf + fbase);
    float4 av = *(const float4*)(aoW + fbase);
    float4 mv = *(const float4*)(mctx + fbase);
    float v[4];
    {
        float gg;
        gg = sigmoidf_(gv.x); v[0] = xv.x + gg * av.x + (1.0f - gg) * mv.x;
        gg = sigmoidf_(gv.y); v[1] = xv.y + gg * av.y + (1.0f - gg) * mv.y;
        gg = sigmoidf_(gv.z); v[2] = xv.z + gg * av.z + (1.0f - gg) * mv.z;
        gg = sigmoidf_(gv.w); v[3] = xv.w + gg * av.w + (1.0f - gg) * mv.w;
    }
    *(float4*)(og + xbase) = (float4){v[0], v[1], v[2], v[3]};
    float ls = v[0] + v[1] + v[2] + v[3];
    #pragma unroll
    for (int off = 32; off >= 1; off >>= 1) ls += __shfl_down(ls, off, 64);
    if ((t & 63) == 0) sbuf[t >> 6] = ls;
    __syncthreads();
    float mean = (sbuf[0] + sbuf[1] + sbuf[2] + sbuf[3]) * (1.0f / D_);
    __syncthreads();
    float lv = 0.f;
    #pragma unroll
    for (int i = 0; i < 4; i++) { float d = v[i] - mean; lv += d * d; }
    #pragma unroll
    for (int off = 32; off >= 1; off >>= 1) lv += __shfl_down(lv, off, 64);
    if ((t & 63) == 0) sbuf[t >> 6] = lv;
    __syncthreads();
    float var = (sbuf[0] + sbuf[1] + sbuf[2] + sbuf[3]) * (1.0f / D_);
    float r = rsqrtf(var + 1e-5f);
    unsigned short* orow = lnout + (long long)row * D_;
    #pragma unroll
    for (int i = 0; i < 4; i++) {
        int c = t * 4 + i;
        orow[c] = f2b((v[i] - mean) * r * g3[c] + b3[c]);
    }
}

// ---------------------------------------------------------------- km row L2-normalize (bf16 in-place)
__global__ __launch_bounds__(256) void rownorm_b16(unsigned short* __restrict__ a)
{
    __shared__ float sbuf[4];
    int row = blockIdx.x;
    int t = threadIdx.x;
    unsigned short* ar = a + (long long)row * D_;
    ushort4 xv = *(const ushort4*)(ar + t * 4);
    float v0 = b2f(xv.x), v1 = b2f(xv.y), v2 = b2f(xv.z), v3 = b2f(xv.w);
    float ls = v0 * v0 + v1 * v1 + v2 * v2 + v3 * v3;
    #pragma unroll
    for (int off = 32; off >= 1; off >>= 1) ls += __shfl_down(ls, off, 64);
    if ((t & 63) == 0) sbuf[t >> 6] = ls;
    __syncthreads();
    float ss = sbuf[0] + sbuf[1] + sbuf[2] + sbuf[3];
    float sc = rsqrtf(ss + 1e-6f);
    ushort4 ov;
    ov.x = f2b(v0 * sc); ov.y = f2b(v1 * sc); ov.z = f2b(v2 * sc); ov.w = f2b(v3 * sc);
    *(ushort4*)(ar + t * 4) = ov;
}

// ---------------------------------------------------------------- transposes
// out row for input col c = (c>>4)*grpMul + (c&15) + rowAdd.
__global__ __launch_bounds__(256) void transpose_f32_b16(
    const float* __restrict__ in, unsigned short* __restrict__ out,
    int R, int Cc, long long izs, long long ozs, int grpMul, int rowAdd)
{
    __shared__ float tile[32][33];
    int z = blockIdx.z;
    const float* ib = in + (long long)z * izs;
    unsigned short* ob = out + (long long)z * ozs;
    int c0 = blockIdx.x * 32, r0 = blockIdx.y * 32;
    int tx = threadIdx.x & 31, ty = threadIdx.x >> 5;
    #pragma unroll
    for (int i = 0; i < 32; i += 8)
        tile[ty + i][tx] = ib[(long long)(r0 + ty + i) * Cc + c0 + tx];
    __syncthreads();
    #pragma unroll
    for (int i = 0; i < 32; i += 8) {
        int c = c0 + ty + i;
        long long orow = (long long)(c >> 4) * grpMul + (c & 15) + rowAdd;
        ob[orow * R + r0 + tx] = f2b(tile[tx][ty + i]);
    }
}

__global__ __launch_bounds__(256) void transpose_b16_b16(
    const unsigned short* __restrict__ in, unsigned short* __restrict__ out,
    int R, int Cc, long long izs, long long ozs)
{
    __shared__ unsigned short tile[32][33];
    int z = blockIdx.z;
    const unsigned short* ib = in + (long long)z * izs;
    unsigned short* ob = out + (long long)z * ozs;
    int c0 = blockIdx.x * 32, r0 = blockIdx.y * 32;
    int tx = threadIdx.x & 31, ty = threadIdx.x >> 5;
    #pragma unroll
    for (int i = 0; i < 32; i += 8)
        tile[ty + i][tx] = ib[(long long)(r0 + ty + i) * Cc + c0 + tx];
    __syncthreads();
    #pragma unroll
    for (int i = 0; i < 32; i += 8)
        ob[(long long)(c0 + ty + i) * R + r0 + tx] = tile[tx][ty + i];
}

// bffI[(i>>4)*32 + (i&15)] = gate bias; +16 = up bias (16-col pair interleave)
__global__ __launch_bounds__(256) void interleave16(
    const float* __restrict__ a, const float* __restrict__ b, float* __restrict__ o, int n)
{
    int i = blockIdx.x * 256 + threadIdx.x;
    if (i < n) {
        int r = ((i >> 4) << 5) + (i & 15);
        o[r] = a[i];
        o[r + 16] = b[i];
    }
}

// ---------------------------------------------------------------- 256x256 deep-pipeline GEMM
// Reverted to the r4 coarse 2-phase schedule (best measured: 77us/37.5% MfmaUtil on FFN-L;
// the two 8-phase ports regressed to 81-84us). Added: bijective XCD swizzle on the flat
// block id (grids are %8==0) so consecutive blocks sharing an A-row-panel land on the
// same XCD L2 — targets the measured 2x FETCH overfetch (49MB vs 24MB ideal).
// 512 thr = 8 waves (2x4), BK=64, 128 KiB LDS dbuf, counted vmcnt(8), raw barriers,
// both-sides (row&7) XOR swizzle.
// MODE 0: N 16-col-interleaved gate/up pairs -> bf16 silu(gate)*up at [M][N/2].
// MODE 1: col-split (shift 10) bf16 out with optional bias (qkv fusion).
template<int MODE>
__global__ __launch_bounds__(512, 2) void gemm256(
    const unsigned short* __restrict__ A, const unsigned short* __restrict__ BT,
    const float* __restrict__ bias, unsigned short* __restrict__ outB,
    int K, int N, int Mrows)
{
    __shared__ short L[2][2][256 * 64];
    // XCD-aware block remap (bijective; launch guarantees nwg % 8 == 0)
    int nwg = gridDim.x * gridDim.y;
    int flat = blockIdx.y * gridDim.x + blockIdx.x;
    int swz = (flat & 7) * (nwg >> 3) + (flat >> 3);
    int row0 = (swz / gridDim.x) * 256, col0 = (swz % gridDim.x) * 256;
    int t = threadIdx.x;
    int wave = t >> 6, lane = t & 63;
    int wr = wave >> 2, wc = wave & 3;
    int quad = lane >> 4, lo = lane & 15;

    auto STAGE = [&](int buf, int kt) {
        #pragma unroll
        for (int nn = 0; nn < 4; nn++) {
            int c = nn * 512 + t;
            int r = c >> 3, s = c & 7;
            int sc = s ^ (r & 7);
            async_cp16(A + (long long)(row0 + r) * K + kt * 64 + sc * 8,
                       &L[buf][0][(nn * 512 + wave * 64) * 8]);
        }
        #pragma unroll
        for (int nn = 0; nn < 4; nn++) {
            int c = nn * 512 + t;
            int r = c >> 3, s = c & 7;
            int sc = s ^ (r & 7);
            async_cp16(BT + (long long)(col0 + r) * K + kt * 64 + sc * 8,
                       &L[buf][1][(nn * 512 + wave * 64) * 8]);
        }
    };

    floatx4 acc[8][4];
    #pragma unroll
    for (int m = 0; m < 8; m++)
        #pragma unroll
        for (int n = 0; n < 4; n++) acc[m][n] = (floatx4){0.f, 0.f, 0.f, 0.f};

    STAGE(0, 0);
    STAGE(1, 1);

    const int NT = K >> 6;
    for (int kt = 0; kt < NT; ++kt) {
        int cur = kt & 1;
        if (kt == NT - 1) wait_vm0(); else wait_vm8();
        __builtin_amdgcn_s_barrier();
        SBAR();

        short8 af[8][2], bf[4][2];
        #pragma unroll
        for (int m = 0; m < 8; m++)
            #pragma unroll
            for (int ks = 0; ks < 2; ks++) {
                int row = wr * 128 + m * 16 + lo;
                int ch = (ks * 4 + quad) ^ (row & 7);
                af[m][ks] = *(const short8*)&L[cur][0][row * 64 + ch * 8];
            }
        #pragma unroll
        for (int n = 0; n < 4; n++)
            #pragma unroll
            for (int ks = 0; ks < 2; ks++) {
                int row = wc * 64 + n * 16 + lo;
                int ch = (ks * 4 + quad) ^ (row & 7);
                bf[n][ks] = *(const short8*)&L[cur][1][row * 64 + ch * 8];
            }
        // k-slot 0 MFMAs overlap k-slot-1 read latency
        #pragma unroll
        for (int m = 0; m < 8; m++)
            #pragma unroll
            for (int n = 0; n < 4; n++)
                acc[m][n] = __builtin_amdgcn_mfma_f32_16x16x32_bf16(af[m][0], bf[n][0], acc[m][n], 0, 0, 0);

        wait_lgkm0();                       // all reads of L[cur] landed in regs
        SBAR();
        __builtin_amdgcn_s_barrier();       // every wave done reading L[cur]
        SBAR();
        if (kt + 2 < NT) STAGE(cur, kt + 2);   // safe overwrite; overlaps k-slot-1 MFMAs

        #pragma unroll
        for (int m = 0; m < 8; m++)
            #pragma unroll
            for (int n = 0; n < 4; n++)
                acc[m][n] = __builtin_amdgcn_mfma_f32_16x16x32_bf16(af[m][1], bf[n][1], acc[m][n], 0, 0, 0);
    }

    if (MODE == 0) {
        #pragma unroll
        for (int m = 0; m < 8; m++)
            #pragma unroll
            for (int n = 0; n < 4; n += 2) {
                int cg = col0 + wc * 64 + n * 16 + lo;
                float bg = bias ? bias[cg] : 0.f;
                float bu = bias ? bias[cg + 16] : 0.f;
                int fc = ((cg >> 5) << 4) + (cg & 15);
                #pragma unroll
                for (int r = 0; r < 4; r++) {
                    int row = row0 + wr * 128 + m * 16 + quad * 4 + r;
                    float vg = acc[m][n][r] + bg;
                    float vu = acc[m][n + 1][r] + bu;
                    float sg = vg / (1.0f + __expf(-vg));
                    outB[(long long)row * (N >> 1) + fc] = f2b(sg * vu);
                }
            }
    } else {
        #pragma unroll
        for (int m = 0; m < 8; m++)
            #pragma unroll
            for (int n = 0; n < 4; n++) {
                int col = col0 + wc * 64 + n * 16 + lo;
                float bv = bias ? bias[col] : 0.f;
                #pragma unroll
                for (int r = 0; r < 4; r++) {
                    int row = row0 + wr * 128 + m * 16 + quad * 4 + r;
                    long long idx = (((long long)(col >> 10) * Mrows + row) << 10) + (col & 1023);
                    outB[idx] = f2b(acc[m][n][r] + bv);
                }
            }
    }
}

// ---------------------------------------------------------------- 128x128 deep-pipeline core
// 256 thr = 4 waves (2x2), BK=64, 64 KiB LDS dbuf (2 blocks/CU), counted vmcnt(8).
__device__ __forceinline__ void core128(
    const unsigned short* __restrict__ Ab, int lda,
    const unsigned short* __restrict__ Bb, int ldb,
    int row0, int col0, int K,
    short (&L)[2][2][128 * 64], floatx4 (&acc)[4][4])
{
    int t = threadIdx.x;
    int wave = t >> 6, lane = t & 63;
    int wr = wave >> 1, wc = wave & 1;
    int quad = lane >> 4, lo = lane & 15;

    const unsigned short* gA = Ab + (long long)row0 * lda;
    const unsigned short* gB = Bb + (long long)col0 * ldb;

    auto STAGE = [&](int buf, int kt) {
        #pragma unroll
        for (int nn = 0; nn < 4; nn++) {
            int c = nn * 256 + t;
            int r = c >> 3, s = c & 7;
            int sc = s ^ (r & 7);
            async_cp16(gA + (long long)r * lda + kt * 64 + sc * 8,
                       &L[buf][0][(nn * 256 + wave * 64) * 8]);
        }
        #pragma unroll
        for (int nn = 0; nn < 4; nn++) {
            int c = nn * 256 + t;
            int r = c >> 3, s = c & 7;
            int sc = s ^ (r & 7);
            async_cp16(gB + (long long)r * ldb + kt * 64 + sc * 8,
                       &L[buf][1][(nn * 256 + wave * 64) * 8]);
        }
    };

    #pragma unroll
    for (int m = 0; m < 4; m++)
        #pragma unroll
        for (int n = 0; n < 4; n++) acc[m][n] = (floatx4){0.f, 0.f, 0.f, 0.f};

    STAGE(0, 0);
    STAGE(1, 1);

    const int NT = K >> 6;
    for (int kt = 0; kt < NT; ++kt) {
        int cur = kt & 1;
        if (kt == NT - 1) wait_vm0(); else wait_vm8();
        __builtin_amdgcn_s_barrier();
        SBAR();

        short8 af[4][2], bf[4][2];
        #pragma unroll
        for (int m = 0; m < 4; m++)
            #pragma unroll
            for (int ks = 0; ks < 2; ks++) {
                int row = wr * 64 + m * 16 + lo;
                int ch = (ks * 4 + quad) ^ (row & 7);
                af[m][ks] = *(const short8*)&L[cur][0][row * 64 + ch * 8];
            }
        #pragma unroll
        for (int n = 0; n < 4; n++)
            #pragma unroll
            for (int ks = 0; ks < 2; ks++) {
                int row = wc * 64 + n * 16 + lo;
                int ch = (ks * 4 + quad) ^ (row & 7);
                bf[n][ks] = *(const short8*)&L[cur][1][row * 64 + ch * 8];
            }
        #pragma unroll
        for (int m = 0; m < 4; m++)
            #pragma unroll
            for (int n = 0; n < 4; n++)
                acc[m][n] = __builtin_amdgcn_mfma_f32_16x16x32_bf16(af[m][0], bf[n][0], acc[m][n], 0, 0, 0);

        wait_lgkm0();
        SBAR();
        __builtin_amdgcn_s_barrier();
        SBAR();
        if (kt + 2 < NT) STAGE(cur, kt + 2);

        #pragma unroll
        for (int m = 0; m < 4; m++)
            #pragma unroll
            for (int n = 0; n < 4; n++)
                acc[m][n] = __builtin_amdgcn_mfma_f32_16x16x32_bf16(af[m][1], bf[n][1], acc[m][n], 0, 0, 0);
    }
}

// z-batched 128x128 pipelined GEMM. z -> (zlo = z & mask, zhi = z >> zLoBits).
// RESID=0: outF fp32 (z strides) and/or outB bf16 (z strides), bias[z*biasZs + col].
// RESID=1: outF[bb*oBS + s*N + col] = acc + bias + resid[same] (batch-mapped rows).
template<int RESID>
__global__ __launch_bounds__(256, 2) void gemm128p(
    const unsigned short* __restrict__ A, long long AzsLo, long long AzsHi, int zLoBits, int lda,
    const unsigned short* __restrict__ BT, long long BzsLo, long long BzsHi, int ldb,
    const float* __restrict__ bias, long long biasZs,
    float* __restrict__ outF, long long OFzsLo, long long OFzsHi,
    unsigned short* __restrict__ outB, long long OBzsLo, long long OBzsHi,
    int K, int N, int rowsPB, long long oBS, const float* __restrict__ resid)
{
    __shared__ short L[2][2][128 * 64];
    int z = blockIdx.z;
    long long zlo = z & ((1 << zLoBits) - 1);
    long long zhi = z >> zLoBits;
    int row0 = blockIdx.y * 128, col0 = blockIdx.x * 128;
    floatx4 acc[4][4];
    core128(A + zlo * AzsLo + zhi * AzsHi, lda,
            BT + zlo * BzsLo + zhi * BzsHi, ldb, row0, col0, K, L, acc);

    int t = threadIdx.x, wave = t >> 6, lane = t & 63;
    int wr = wave >> 1, wc = wave & 1;
    int quad = lane >> 4, lo = lane & 15;
    long long oF0 = zlo * OFzsLo + zhi * OFzsHi;
    long long oB0 = zlo * OBzsLo + zhi * OBzsHi;
    #pragma unroll
    for (int m = 0; m < 4; m++)
        #pragma unroll
        for (int n = 0; n < 4; n++) {
            int col = col0 + wc * 64 + n * 16 + lo;
            float bv = bias ? bias[(long long)z * biasZs + col] : 0.f;
            #pragma unroll
            for (int r = 0; r < 4; r++) {
                int row = row0 + wr * 64 + m * 16 + quad * 4 + r;
                float v = acc[m][n][r] + bv;
                if (RESID) {
                    int bb = row / rowsPB, s = row - bb * rowsPB;
                    long long oi = (long long)bb * oBS + (long long)s * N + col;
                    outF[oi] = v + resid[oi];
                } else {
                    long long idx = (long long)row * N + col;
                    if (outF) outF[oF0 + idx] = v;
                    if (outB) outB[oB0 + idx] = f2b(v);
                }
            }
        }
}

// serial chunk update: gradT = MTbPrev @ KK - KVT; ST = eta*ST - theta*gradT;
// MT = (1-alpha)*MT + ST; MTbNext = bf16(MT). z = batch (4).
__global__ __launch_bounds__(256, 2) void gemm128_mupd(
    const unsigned short* __restrict__ Ap, const unsigned short* __restrict__ Bp,
    const unsigned short* __restrict__ KVT,
    float* __restrict__ ST, float* __restrict__ MT, unsigned short* __restrict__ MTbN,
    const float* __restrict__ lr, const float* __restrict__ mom, const float* __restrict__ fg)
{
    __shared__ short L[2][2][128 * 64];
    int z = blockIdx.z;
    long long zb = (long long)z * D_ * D_;
    int row0 = blockIdx.y * 128, col0 = blockIdx.x * 128;
    floatx4 acc[4][4];
    core128(Ap + zb, D_, Bp + zb, D_, row0, col0, D_, L, acc);

    int t = threadIdx.x, wave = t >> 6, lane = t & 63;
    int wr = wave >> 1, wc = wave & 1;
    int quad = lane >> 4, lo = lane & 15;
    float theta = sigmoidf_(lr[0]) * (1.0f / C_);
    float eta   = sigmoidf_(mom[0]);
    float alpha = sigmoidf_(fg[0]);
    #pragma unroll
    for (int m = 0; m < 4; m++)
        #pragma unroll
        for (int n = 0; n < 4; n++) {
            int col = col0 + wc * 64 + n * 16 + lo;
            #pragma unroll
            for (int r = 0; r < 4; r++) {
                int row = row0 + wr * 64 + m * 16 + quad * 4 + r;
                long long idx = zb + (long long)row * D_ + col;
                float gv = acc[m][n][r] - b2f(KVT[idx]);
                float st = eta * ST[idx] - theta * gv;
                ST[idx] = st;
                float mm = (1.0f - alpha) * MT[idx] + st;
                MT[idx] = mm;
                MTbN[idx] = f2b(mm);
            }
        }
}

// ---------------------------------------------------------------- MFMA flash attention (group-batched)
__global__ __launch_bounds__(256) void attn_mfma(
    const unsigned short* __restrict__ qh, const unsigned short* __restrict__ kh,
    const unsigned short* __restrict__ vh,
    const float* __restrict__ pk, const float* __restrict__ pv,
    unsigned short* __restrict__ ao, int GC)
{
    __shared__ __align__(16) short Ks[64][KP_];
    __shared__ __align__(16) short Vs[64][KP_];
    __shared__ __align__(16) short Ps[4][16][KP_];
    int qb = blockIdx.x, h = blockIdx.y, b = blockIdx.z;
    int q0 = qb * 64;
    int kbase = q0 & ~(C_ - 1);
    int t = threadIdx.x;
    int wave = t >> 6, lane = t & 63;
    int quad = lane >> 4, lo = lane & 15;

    short8 qf[2];
    {
        const unsigned short* qp = qh + (long long)(b * GC + q0 + wave * 16 + lo) * (H_ * DH_)
                                   + h * DH_ + quad * 8;
        qf[0] = *(const short8*)qp;
        qf[1] = *(const short8*)(qp + 32);
    }
    floatx4 o4[4];
    #pragma unroll
    for (int dt = 0; dt < 4; dt++) o4[dt] = (floatx4){0.f, 0.f, 0.f, 0.f};
    float m[4], l[4];
    #pragma unroll
    for (int r = 0; r < 4; r++) { m[r] = -1e30f; l[r] = 0.f; }
    {
        short* pz = &Ps[wave][lo][16 + quad * 4];
        pz[0] = 0; pz[1] = 0; pz[2] = 0; pz[3] = 0;
    }

    int ktmax = ((q0 - kbase) >> 6) + 1;
    for (int kt = 0; kt <= ktmax; kt++) {
        __syncthreads();
        if (kt == 0) {
            int key = t >> 4, d4 = (t & 15) * 4;
            float4 kv4 = *(const float4*)(pk + ((long long)key * H_ + h) * DH_ + d4);
            Ks[key][d4 + 0] = f2b(kv4.x); Ks[key][d4 + 1] = f2b(kv4.y);
            Ks[key][d4 + 2] = f2b(kv4.z); Ks[key][d4 + 3] = f2b(kv4.w);
            float4 vv4 = *(const float4*)(pv + ((long long)key * H_ + h) * DH_ + d4);
            Vs[d4 + 0][key] = f2b(vv4.x); Vs[d4 + 1][key] = f2b(vv4.y);
            Vs[d4 + 2][key] = f2b(vv4.z); Vs[d4 + 3][key] = f2b(vv4.w);
            int dz = t >> 2, kz = 16 + (t & 3) * 4;
            Vs[dz][kz + 0] = 0; Vs[dz][kz + 1] = 0;
            Vs[dz][kz + 2] = 0; Vs[dz][kz + 3] = 0;
        } else {
            int tok0 = kbase + (kt - 1) * 64;
            {
                int key = t >> 2, dblk = (t & 3) * 16;
                const unsigned short* kp2 = kh + (long long)(b * GC + tok0 + key) * (H_ * DH_)
                                            + h * DH_ + dblk;
                *(short8*)&Ks[key][dblk]     = *(const short8*)kp2;
                *(short8*)&Ks[key][dblk + 8] = *(const short8*)(kp2 + 8);
            }
            {
                int kp = t & 31, dg = t >> 5;
                const unsigned short* vp0 = vh + (long long)(b * GC + tok0 + 2 * kp) * (H_ * DH_)
                                            + h * DH_ + dg * 8;
                short8 v0 = *(const short8*)vp0;
                short8 v1 = *(const short8*)(vp0 + H_ * DH_);
                #pragma unroll
                for (int j = 0; j < 8; j++) {
                    unsigned int pk2 = ((unsigned int)(unsigned short)v1[j] << 16)
                                     | (unsigned short)v0[j];
                    *(unsigned int*)&Vs[dg * 8 + j][2 * kp] = pk2;
                }
            }
        }
        __syncthreads();

        int ntiles = (kt == 0) ? 1 : 4;
        floatx4 s4[4];
        #pragma unroll
        for (int nt = 0; nt < 4; nt++) {
            if (nt >= ntiles) break;
            s4[nt] = (floatx4){0.f, 0.f, 0.f, 0.f};
            #pragma unroll
            for (int ks = 0; ks < 2; ks++) {
                short8 bfr = *(const short8*)&Ks[nt * 16 + lo][ks * 32 + quad * 8];
                s4[nt] = __builtin_amdgcn_mfma_f32_16x16x32_bf16(qf[ks], bfr, s4[nt], 0, 0, 0);
            }
        }
        bool diag = (kt == ktmax);
        int key0 = kbase + (kt - 1) * 64;
        #pragma unroll
        for (int nt = 0; nt < 4; nt++) {
            if (nt >= ntiles) break;
            #pragma unroll
            for (int r = 0; r < 4; r++) {
                float v = s4[nt][r] * 0.125f;
                if (diag) {
                    int kg = key0 + nt * 16 + lo;
                    int qq = q0 + wave * 16 + quad * 4 + r;
                    if (kg > qq) v = -1e30f;
                }
                s4[nt][r] = v;
            }
        }
        float alpha[4];
        #pragma unroll
        for (int r = 0; r < 4; r++) {
            float tm = s4[0][r];
            #pragma unroll
            for (int nt = 1; nt < 4; nt++) { if (nt >= ntiles) break; tm = fmaxf(tm, s4[nt][r]); }
            #pragma unroll
            for (int msk = 1; msk <= 8; msk <<= 1) tm = fmaxf(tm, __shfl_xor(tm, msk, 64));
            float mn = fmaxf(m[r], tm);
            alpha[r] = __expf(m[r] - mn);
            float sum = 0.f;
            #pragma unroll
            for (int nt = 0; nt < 4; nt++) {
                if (nt >= ntiles) break;
                float p = __expf(s4[nt][r] - mn);
                sum += p;
                Ps[wave][quad * 4 + r][nt * 16 + lo] = f2b(p);
            }
            #pragma unroll
            for (int msk = 1; msk <= 8; msk <<= 1) sum += __shfl_xor(sum, msk, 64);
            l[r] = l[r] * alpha[r] + sum;
            m[r] = mn;
        }
        #pragma unroll
        for (int dt = 0; dt < 4; dt++)
            #pragma unroll
            for (int r = 0; r < 4; r++) o4[dt][r] *= alpha[r];
        __syncthreads();
        int ksteps = (kt == 0) ? 1 : 2;
        #pragma unroll
        for (int ks = 0; ks < 2; ks++) {
            if (ks >= ksteps) break;
            short8 afr = *(const short8*)&Ps[wave][lo][ks * 32 + quad * 8];
            #pragma unroll
            for (int dt = 0; dt < 4; dt++) {
                short8 bfr = *(const short8*)&Vs[dt * 16 + lo][ks * 32 + quad * 8];
                o4[dt] = __builtin_amdgcn_mfma_f32_16x16x32_bf16(afr, bfr, o4[dt], 0, 0, 0);
            }
        }
    }
    #pragma unroll
    for (int r = 0; r < 4; r++) {
        float inv = 1.0f / l[r];
        int q = q0 + wave * 16 + quad * 4 + r;
        unsigned short* aop = ao + (long long)(b * GC + q) * (H_ * DH_) + h * DH_ + lo;
        #pragma unroll
        for (int dt = 0; dt < 4; dt++) aop[dt * 16] = f2b(o4[dt][r] * inv);
    }
}

// ---------------------------------------------------------------- launch
extern "C" void kernel_launch(void* const* d_in, const int* in_sizes, int n_in,
                              void* d_out, int out_size, void* d_ws, size_t ws_size,
                              hipStream_t stream)
{
    const float* x     = (const float*)d_in[0];
    const float* g1    = (const float*)d_in[1];
    const float* b1    = (const float*)d_in[2];
    const float* g2    = (const float*)d_in[3];
    const float* b2    = (const float*)d_in[4];
    const float* g3    = (const float*)d_in[5];
    const float* b3    = (const float*)d_in[6];
    const float* Wqm   = (const float*)d_in[7];
    const float* Wkm   = (const float*)d_in[8];
    const float* Wvm   = (const float*)d_in[9];
    const float* lr    = (const float*)d_in[10];
    const float* mom   = (const float*)d_in[11];
    const float* fg    = (const float*)d_in[12];
    const float* Wq    = (const float*)d_in[13];
    const float* bq    = (const float*)d_in[14];
    const float* Wk    = (const float*)d_in[15];
    const float* bk    = (const float*)d_in[16];
    const float* Wv    = (const float*)d_in[17];
    const float* bv    = (const float*)d_in[18];
    const float* Wo    = (const float*)d_in[19];
    const float* bo    = (const float*)d_in[20];
    const float* pk    = (const float*)d_in[21];
    const float* pv    = (const float*)d_in[22];
    const float* Wg    = (const float*)d_in[23];
    const float* bg    = (const float*)d_in[24];
    const float* Wgate = (const float*)d_in[25];
    const float* bgate = (const float*)d_in[26];
    const float* Wup   = (const float*)d_in[27];
    const float* bup   = (const float*)d_in[28];
    const float* Wdown = (const float*)d_in[29];
    const float* bdown = (const float*)d_in[30];
    float* out = (float*)d_out;

    const long long MiB = 1024LL * 1024LL;
    const long long D2 = (long long)D_ * D_;
    char* w = (char*)d_ws;

    // ---- group size: total = 82 + 60*G MiB (G in {8,4,2,1})
    int G = 8;
    while (G > 1 && (size_t)((82 + 60 * G) * MiB) > ws_size) G >>= 1;
    const int GC = G * C_;
    const int NG = NC_ / G;
    const int RG = B_ * GC;
    const int RING = G + 1;
    int gcShift = 0; while ((1 << gcShift) < GC) gcShift++;
    const long long GiM = (long long)G * MiB;

    // ---- fixed region
    float* MT  = (float*)(w + 0 * MiB);                          // 16
    float* ST  = (float*)(w + 16 * MiB);                         // 16
    unsigned short* MTb = (unsigned short*)(w + 32 * MiB);       // 8*(G+1) ring of bf16 M^T
    char* wt = w + (32 + 8 * (long long)RING) * MiB;
    unsigned short* WqkvmT = (unsigned short*)(wt + 0 * MiB);    // 6
    unsigned short* WqkvhT = (unsigned short*)(wt + 6 * MiB);    // 6
    unsigned short* WoT    = (unsigned short*)(wt + 12 * MiB);   // 2
    unsigned short* WgT    = (unsigned short*)(wt + 14 * MiB);   // 2
    unsigned short* WffT   = (unsigned short*)(wt + 16 * MiB);   // 16 [8192][1024] 16-col-pair interleave
    unsigned short* WdownT = (unsigned short*)(wt + 32 * MiB);   // 8
    float* bqkvh = (float*)(wt + 40 * MiB);                      // 12 KB
    float* bffI  = (float*)(wt + 40 * MiB + 65536);              // 32 KB interleaved
    float* bog   = (float*)(wt + 40 * MiB + 131072);             // 8 KB
    char* gbase = wt + 41 * MiB;

    // ---- group region (G·MiB units)
    unsigned short* QKVm   = (unsigned short*)(gbase);                 // qm|km|vm, later qh|kh|vh
    unsigned short* kmTG   = (unsigned short*)(gbase + 12 * GiM);      // [b][D][GC]; later Hao
    unsigned short* vmTG   = (unsigned short*)(gbase + 16 * GiM);      // [b][D][GC]
    unsigned short* KK     = (unsigned short*)(gbase + 20 * GiM);      // [j][b][D][D] bf16
    unsigned short* KVT    = (unsigned short*)(gbase + 28 * GiM);      // [j][b][D][D] bf16
    float* mctx32          = (float*)(gbase + 36 * GiM);
    unsigned short* mctx16 = (unsigned short*)(gbase + 44 * GiM);
    unsigned short* LNout  = (unsigned short*)(gbase + 48 * GiM);
    // overlays (dead-by-then regions)
    unsigned short* Hao = kmTG;
    float* aoW = (float*)KK;
    float* gG  = (float*)KVT;
    unsigned short* G0 = QKVm;

    hipMemsetAsync(d_ws, 0, (size_t)((32 + 8 * (long long)RING) * MiB), stream);  // MT, ST, MTb ring

    // concat / interleave biases
    hipMemcpyAsync(bqkvh,        bq, 4096, hipMemcpyDeviceToDevice, stream);
    hipMemcpyAsync(bqkvh + 1024, bk, 4096, hipMemcpyDeviceToDevice, stream);
    hipMemcpyAsync(bqkvh + 2048, bv, 4096, hipMemcpyDeviceToDevice, stream);
    hipMemcpyAsync(bog,          bo, 4096, hipMemcpyDeviceToDevice, stream);
    hipMemcpyAsync(bog + 1024,   bg, 4096, hipMemcpyDeviceToDevice, stream);
    interleave16<<<16, 256, 0, stream>>>(bgate, bup, bffI, FF_);

    // weight transposes -> bf16 [N][K]; Wgate/Wup 16-col-pair interleaved into WffT
    transpose_f32_b16<<<dim3(32, 32, 1), 256, 0, stream>>>(Wqm, WqkvmT,           D_, D_, 0, 0, 16, 0);
    transpose_f32_b16<<<dim3(32, 32, 1), 256, 0, stream>>>(Wkm, WqkvmT + 1048576, D_, D_, 0, 0, 16, 0);
    transpose_f32_b16<<<dim3(32, 32, 1), 256, 0, stream>>>(Wvm, WqkvmT + 2097152, D_, D_, 0, 0, 16, 0);
    transpose_f32_b16<<<dim3(32, 32, 1), 256, 0, stream>>>(Wq,  WqkvhT,           D_, D_, 0, 0, 16, 0);
    transpose_f32_b16<<<dim3(32, 32, 1), 256, 0, stream>>>(Wk,  WqkvhT + 1048576, D_, D_, 0, 0, 16, 0);
    transpose_f32_b16<<<dim3(32, 32, 1), 256, 0, stream>>>(Wv,  WqkvhT + 2097152, D_, D_, 0, 0, 16, 0);
    transpose_f32_b16<<<dim3(32, 32, 1), 256, 0, stream>>>(Wo,  WoT,              D_, D_, 0, 0, 16, 0);
    transpose_f32_b16<<<dim3(32, 32, 1), 256, 0, stream>>>(Wg,  WgT,              D_, D_, 0, 0, 16, 0);
    transpose_f32_b16<<<dim3(128, 32, 1), 256, 0, stream>>>(Wgate, WffT,          D_, FF_, 0, 0, 32, 0);
    transpose_f32_b16<<<dim3(128, 32, 1), 256, 0, stream>>>(Wup,   WffT,          D_, FF_, 0, 0, 32, 16);
    transpose_f32_b16<<<dim3(32, 128, 1), 256, 0, stream>>>(Wdown, WdownT,        FF_, D_, 0, 0, 16, 0);

    const long long xBS = (long long)S_ * D_;

    for (int g = 0; g < NG; g++) {
        const float* xg = x   + (long long)g * GC * D_;
        float* og       = out + (long long)g * GC * D_;
        int s0 = (g * G) % RING;

        // A) h1 = LN1(x) -> LNout
        ln_kernel<<<RG, 256, 0, stream>>>(xg, xBS, GC, nullptr, g1, b1, LNout);
        // B) qm|km|vm -> QKVm (col-split slots of [RG][1024])
        gemm256<1><<<dim3(12, RG / 256), 512, 0, stream>>>(LNout, WqkvmT, nullptr, QKVm, D_, 3072, RG);
        // C) km normalize; kmT, vmT -> [b][D][GC]
        rownorm_b16<<<RG, 256, 0, stream>>>(QKVm + (long long)RG * D_);
        transpose_b16_b16<<<dim3(32, GC / 32, 4), 256, 0, stream>>>(QKVm + (long long)RG * D_,
            kmTG, GC, D_, (long long)GC * D_, (long long)D_ * GC);
        transpose_b16_b16<<<dim3(32, GC / 32, 4), 256, 0, stream>>>(QKVm + 2LL * RG * D_,
            vmTG, GC, D_, (long long)GC * D_, (long long)D_ * GC);
        // D1) KK[j][b] = kmT_j . km_j  (zlo=b, zhi=j)
        gemm128p<0><<<dim3(8, 8, 4 * G), 256, 0, stream>>>(
            kmTG, (long long)D_ * GC, (long long)C_, 2, GC,
            kmTG, (long long)D_ * GC, (long long)C_, GC,
            nullptr, 0,
            nullptr, 0, 0,
            KK, D2, 4 * D2,
            C_, D_, 0, 0, nullptr);
        // D2) KVT[j][b] = vmT_j . km_j
        gemm128p<0><<<dim3(8, 8, 4 * G), 256, 0, stream>>>(
            vmTG, (long long)D_ * GC, (long long)C_, 2, GC,
            kmTG, (long long)D_ * GC, (long long)C_, GC,
            nullptr, 0,
            nullptr, 0, 0,
            KVT, D2, 4 * D2,
            C_, D_, 0, 0, nullptr);
        // D3) serial chain: one fused GEMM+update per chunk
        for (int j = 0; j < G; j++) {
            int sp = (s0 + j) % RING, sn = (s0 + j + 1) % RING;
            gemm128_mupd<<<dim3(8, 8, 4), 256, 0, stream>>>(
                MTb + (long long)sp * 4 * D2, KK + (long long)j * 4 * D2,
                KVT + (long long)j * 4 * D2, ST, MT, MTb + (long long)sn * 4 * D2,
                lr, mom, fg);
        }
        // D4) mem_ctx = qm_j @ M_{j-1}
        if (G <= 2) {
            long long stride = (G == 2) ? (((s0 + 1) % RING) - s0) : 0;
            gemm128p<0><<<dim3(8, 4, 4 * G), 256, 0, stream>>>(
                QKVm, (long long)GC * D_, (long long)C_ * D_, 2, D_,
                MTb + (long long)s0 * 4 * D2, D2, stride * 4 * D2, D_,
                nullptr, 0,
                mctx32, (long long)GC * D_, (long long)C_ * D_,
                mctx16, (long long)GC * D_, (long long)C_ * D_,
                D_, D_, 0, 0, nullptr);
        } else {
            for (int j = 0; j < G; j++) {
                int sp = (s0 + j) % RING;
                gemm128p<0><<<dim3(8, 4, 4), 256, 0, stream>>>(
                    QKVm + (long long)j * C_ * D_, (long long)GC * D_, 0, 2, D_,
                    MTb + (long long)sp * 4 * D2, D2, 0, D_,
                    nullptr, 0,
                    mctx32 + (long long)j * C_ * D_, (long long)GC * D_, 0,
                    mctx16 + (long long)j * C_ * D_, (long long)GC * D_, 0,
                    D_, D_, 0, 0, nullptr);
            }
        }
        // E) h2 = LN2(x + mem_ctx) -> LNout
        ln_kernel<<<RG, 256, 0, stream>>>(xg, xBS, GC, mctx32, g2, b2, LNout);
        // F) qh|kh|vh -> QKVm
        gemm256<1><<<dim3(12, RG / 256), 512, 0, stream>>>(LNout, WqkvhT, bqkvh, QKVm, D_, 3072, RG);
        // G) attention -> Hao
        attn_mfma<<<dim3(GC / 64, H_, B_), 256, 0, stream>>>(QKVm, QKVm + (long long)RG * D_,
            QKVm + 2LL * RG * D_, pk, pv, Hao, GC);
        // H+I) z=0: aoW = Hao@Wo+bo ; z=1: gG = mctx16@Wg+bg
        gemm128p<0><<<dim3(8, RG / 128, 2), 256, 0, stream>>>(
            Hao, (long long)(mctx16 - Hao), 0, 30, D_,
            WoT, (long long)(WgT - WoT), 0, D_,
            bog, 1024,
            aoW, (long long)(gG - aoW), 0,
            nullptr, 0, 0,
            D_, D_, 0, 0, nullptr);
        // J) fused gate-combine + LN3 -> og, LNout
        gate_ln_kernel<<<RG, 256, 0, stream>>>(xg, xBS, gcShift, gG, aoW, mctx32,
            g3, b3, og, LNout);
        // L) FFN gate|up 16-pair interleaved, fused silu*up -> G0 [RG][4096] bf16
        gemm256<0><<<dim3(32, RG / 256), 512, 0, stream>>>(LNout, WffT, bffI, G0, D_, 8192, 0);
        // N) out = o + prod @ Wdown + bdown
        gemm128p<1><<<dim3(8, RG / 128, 1), 256, 0, stream>>>(
            G0, 0, 0, 0, FF_,
            WdownT, 0, 0, FF_,
            bdown, 0,
            og, 0, 0,
            nullptr, 0, 0,
            FF_, D_, GC, xBS, og);
    }
}

// Round 9
// 1904.431 us; speedup vs baseline: 1.0385x; 1.0015x over previous
//
#include <hip/hip_runtime.h>
#include <hip/hip_bf16.h>
#include <math.h>

#define D_ 1024
#define C_ 512
#define H_ 16
#define DH_ 64
#define P_ 16
#define FF_ 4096
#define S_ 4096
#define B_ 4
#define NC_ 8
#define KP_ 72   // attn LDS pitch (shorts)

typedef __attribute__((ext_vector_type(8))) short short8;
typedef __attribute__((ext_vector_type(4))) float floatx4;

__device__ __forceinline__ float sigmoidf_(float x) { return 1.0f / (1.0f + __expf(-x)); }
__device__ __forceinline__ unsigned short f2b(float x) {
    __hip_bfloat16 h = __float2bfloat16(x);
    return __builtin_bit_cast(unsigned short, h);
}
__device__ __forceinline__ float b2f(unsigned short u) {
    __hip_bfloat16 h = __builtin_bit_cast(__hip_bfloat16, u);
    return __bfloat162float(h);
}
// async global->LDS 16B: LDS dst = wave-uniform base + lane*16
__device__ __forceinline__ void async_cp16(const unsigned short* g, short* l) {
    __builtin_amdgcn_global_load_lds(
        (const __attribute__((address_space(1))) void*)g,
        (__attribute__((address_space(3))) void*)l, 16, 0, 0);
}
__device__ __forceinline__ void wait_vm8()   { asm volatile("s_waitcnt vmcnt(8)" ::: "memory"); }
__device__ __forceinline__ void wait_vm0()   { asm volatile("s_waitcnt vmcnt(0)" ::: "memory"); }
__device__ __forceinline__ void wait_lgkm0() { asm volatile("s_waitcnt lgkmcnt(0)" ::: "memory"); }
#define SBAR() __builtin_amdgcn_sched_barrier(0)

// ---------------------------------------------------------------- LayerNorm (fp32 in, bf16 out)
// add: optional fp32 addend; addb: optional bf16 addend (at [row][D] layout)
__global__ __launch_bounds__(256) void ln_kernel(
    const float* __restrict__ x, long long xBatchStride, int rowsPerBatch,
    const float* __restrict__ add, const unsigned short* __restrict__ addb,
    const float* __restrict__ g, const float* __restrict__ beta,
    unsigned short* __restrict__ out)
{
    __shared__ float sbuf[4];
    int row = blockIdx.x;
    int bb = row / rowsPerBatch, s = row - bb * rowsPerBatch;
    const float* xr = x + (long long)bb * xBatchStride + (long long)s * D_;
    int t = threadIdx.x;
    float v[4];
    float4 xv = *(const float4*)(xr + t * 4);
    v[0] = xv.x; v[1] = xv.y; v[2] = xv.z; v[3] = xv.w;
    if (add) {
        float4 av = *(const float4*)(add + (long long)row * D_ + t * 4);
        v[0] += av.x; v[1] += av.y; v[2] += av.z; v[3] += av.w;
    }
    if (addb) {
        ushort4 ab = *(const ushort4*)(addb + (long long)row * D_ + t * 4);
        v[0] += b2f(ab.x); v[1] += b2f(ab.y); v[2] += b2f(ab.z); v[3] += b2f(ab.w);
    }
    float ls = v[0] + v[1] + v[2] + v[3];
    #pragma unroll
    for (int off = 32; off >= 1; off >>= 1) ls += __shfl_down(ls, off, 64);
    if ((t & 63) == 0) sbuf[t >> 6] = ls;
    __syncthreads();
    float mean = (sbuf[0] + sbuf[1] + sbuf[2] + sbuf[3]) * (1.0f / D_);
    __syncthreads();
    float lv = 0.f;
    #pragma unroll
    for (int i = 0; i < 4; i++) { float d = v[i] - mean; lv += d * d; }
    #pragma unroll
    for (int off = 32; off >= 1; off >>= 1) lv += __shfl_down(lv, off, 64);
    if ((t & 63) == 0) sbuf[t >> 6] = lv;
    __syncthreads();
    float var = (sbuf[0] + sbuf[1] + sbuf[2] + sbuf[3]) * (1.0f / D_);
    float r = rsqrtf(var + 1e-5f);
    unsigned short* orow = out + (long long)row * D_;
    #pragma unroll
    for (int i = 0; i < 4; i++) {
        int c = t * 4 + i;
        orow[c] = f2b((v[i] - mean) * r * g[c] + beta[c]);
    }
}

// ---------------------------------------------------------------- fused gate-combine + LN3 (mctx bf16)
__global__ __launch_bounds__(256) void gate_ln_kernel(
    const float* __restrict__ x, long long xBS, int gcShift,
    const float* __restrict__ gbuf, const float* __restrict__ aoW,
    const unsigned short* __restrict__ mctx,
    const float* __restrict__ g3, const float* __restrict__ b3,
    float* __restrict__ og, unsigned short* __restrict__ lnout)
{
    __shared__ float sbuf[4];
    int row = blockIdx.x;
    int bb = row >> gcShift, s = row & ((1 << gcShift) - 1);
    int t = threadIdx.x;
    long long fbase = (long long)row * D_ + t * 4;
    long long xbase = (long long)bb * xBS + (long long)s * D_ + t * 4;
    float4 xv = *(const float4*)(x + xbase);
    float4 gv = *(const float4*)(gbuf + fbase);
    float4 av = *(const float4*)(aoW + fbase);
    ushort4 mb = *(const ushort4*)(mctx + fbase);
    float mv[4] = { b2f(mb.x), b2f(mb.y), b2f(mb.z), b2f(mb.w) };
    float v[4];
    {
        float gg;
        gg = sigmoidf_(gv.x); v[0] = xv.x + gg * av.x + (1.0f - gg) * mv[0];
        gg = sigmoidf_(gv.y); v[1] = xv.y + gg * av.y + (1.0f - gg) * mv[1];
        gg = sigmoidf_(gv.z); v[2] = xv.z + gg * av.z + (1.0f - gg) * mv[2];
        gg = sigmoidf_(gv.w); v[3] = xv.w + gg * av.w + (1.0f - gg) * mv[3];
    }
    *(float4*)(og + xbase) = (float4){v[0], v[1], v[2], v[3]};
    float ls = v[0] + v[1] + v[2] + v[3];
    #pragma unroll
    for (int off = 32; off >= 1; off >>= 1) ls += __shfl_down(ls, off, 64);
    if ((t & 63) == 0) sbuf[t >> 6] = ls;
    __syncthreads();
    float mean = (sbuf[0] + sbuf[1] + sbuf[2] + sbuf[3]) * (1.0f / D_);
    __syncthreads();
    float lv = 0.f;
    #pragma unroll
    for (int i = 0; i < 4; i++) { float d = v[i] - mean; lv += d * d; }
    #pragma unroll
    for (int off = 32; off >= 1; off >>= 1) lv += __shfl_down(lv, off, 64);
    if ((t & 63) == 0) sbuf[t >> 6] = lv;
    __syncthreads();
    float var = (sbuf[0] + sbuf[1] + sbuf[2] + sbuf[3]) * (1.0f / D_);
    float r = rsqrtf(var + 1e-5f);
    unsigned short* orow = lnout + (long long)row * D_;
    #pragma unroll
    for (int i = 0; i < 4; i++) {
        int c = t * 4 + i;
        orow[c] = f2b((v[i] - mean) * r * g3[c] + b3[c]);
    }
}

// ---------------------------------------------------------------- km row L2-normalize (bf16 in-place)
__global__ __launch_bounds__(256) void rownorm_b16(unsigned short* __restrict__ a)
{
    __shared__ float sbuf[4];
    int row = blockIdx.x;
    int t = threadIdx.x;
    unsigned short* ar = a + (long long)row * D_;
    ushort4 xv = *(const ushort4*)(ar + t * 4);
    float v0 = b2f(xv.x), v1 = b2f(xv.y), v2 = b2f(xv.z), v3 = b2f(xv.w);
    float ls = v0 * v0 + v1 * v1 + v2 * v2 + v3 * v3;
    #pragma unroll
    for (int off = 32; off >= 1; off >>= 1) ls += __shfl_down(ls, off, 64);
    if ((t & 63) == 0) sbuf[t >> 6] = ls;
    __syncthreads();
    float ss = sbuf[0] + sbuf[1] + sbuf[2] + sbuf[3];
    float sc = rsqrtf(ss + 1e-6f);
    ushort4 ov;
    ov.x = f2b(v0 * sc); ov.y = f2b(v1 * sc); ov.z = f2b(v2 * sc); ov.w = f2b(v3 * sc);
    *(ushort4*)(ar + t * 4) = ov;
}

// ---------------------------------------------------------------- transposes
// out row for input col c = (c>>4)*grpMul + (c&15) + rowAdd.
__global__ __launch_bounds__(256) void transpose_f32_b16(
    const float* __restrict__ in, unsigned short* __restrict__ out,
    int R, int Cc, long long izs, long long ozs, int grpMul, int rowAdd)
{
    __shared__ float tile[32][33];
    int z = blockIdx.z;
    const float* ib = in + (long long)z * izs;
    unsigned short* ob = out + (long long)z * ozs;
    int c0 = blockIdx.x * 32, r0 = blockIdx.y * 32;
    int tx = threadIdx.x & 31, ty = threadIdx.x >> 5;
    #pragma unroll
    for (int i = 0; i < 32; i += 8)
        tile[ty + i][tx] = ib[(long long)(r0 + ty + i) * Cc + c0 + tx];
    __syncthreads();
    #pragma unroll
    for (int i = 0; i < 32; i += 8) {
        int c = c0 + ty + i;
        long long orow = (long long)(c >> 4) * grpMul + (c & 15) + rowAdd;
        ob[orow * R + r0 + tx] = f2b(tile[tx][ty + i]);
    }
}

__global__ __launch_bounds__(256) void transpose_b16_b16(
    const unsigned short* __restrict__ in, unsigned short* __restrict__ out,
    int R, int Cc, long long izs, long long ozs)
{
    __shared__ unsigned short tile[32][33];
    int z = blockIdx.z;
    const unsigned short* ib = in + (long long)z * izs;
    unsigned short* ob = out + (long long)z * ozs;
    int c0 = blockIdx.x * 32, r0 = blockIdx.y * 32;
    int tx = threadIdx.x & 31, ty = threadIdx.x >> 5;
    #pragma unroll
    for (int i = 0; i < 32; i += 8)
        tile[ty + i][tx] = ib[(long long)(r0 + ty + i) * Cc + c0 + tx];
    __syncthreads();
    #pragma unroll
    for (int i = 0; i < 32; i += 8)
        ob[(long long)(c0 + ty + i) * R + r0 + tx] = tile[tx][ty + i];
}

// bffI[(i>>4)*32 + (i&15)] = gate bias; +16 = up bias (16-col pair interleave)
__global__ __launch_bounds__(256) void interleave16(
    const float* __restrict__ a, const float* __restrict__ b, float* __restrict__ o, int n)
{
    int i = blockIdx.x * 256 + threadIdx.x;
    if (i < n) {
        int r = ((i >> 4) << 5) + (i & 15);
        o[r] = a[i];
        o[r + 16] = b[i];
    }
}

// ---------------------------------------------------------------- 256x256 deep-pipeline GEMM
// r4 coarse 2-phase schedule, plain block mapping (best measured: 77us / 37.5% MfmaUtil,
// FETCH 49MB; XCD swizzle experiment TRIPLED FETCH to 135MB — reverted).
// 512 thr = 8 waves (2x4), BK=64, 128 KiB LDS dbuf, counted vmcnt(8), raw barriers,
// both-sides (row&7) XOR swizzle.
// MODE 0: N 16-col-interleaved gate/up pairs -> bf16 silu(gate)*up at [M][N/2].
// MODE 1: col-split (shift 10) bf16 out with optional bias (qkv fusion).
template<int MODE>
__global__ __launch_bounds__(512, 2) void gemm256(
    const unsigned short* __restrict__ A, const unsigned short* __restrict__ BT,
    const float* __restrict__ bias, unsigned short* __restrict__ outB,
    int K, int N, int Mrows)
{
    __shared__ short L[2][2][256 * 64];
    int row0 = blockIdx.y * 256, col0 = blockIdx.x * 256;
    int t = threadIdx.x;
    int wave = t >> 6, lane = t & 63;
    int wr = wave >> 2, wc = wave & 3;
    int quad = lane >> 4, lo = lane & 15;

    auto STAGE = [&](int buf, int kt) {
        #pragma unroll
        for (int nn = 0; nn < 4; nn++) {
            int c = nn * 512 + t;
            int r = c >> 3, s = c & 7;
            int sc = s ^ (r & 7);
            async_cp16(A + (long long)(row0 + r) * K + kt * 64 + sc * 8,
                       &L[buf][0][(nn * 512 + wave * 64) * 8]);
        }
        #pragma unroll
        for (int nn = 0; nn < 4; nn++) {
            int c = nn * 512 + t;
            int r = c >> 3, s = c & 7;
            int sc = s ^ (r & 7);
            async_cp16(BT + (long long)(col0 + r) * K + kt * 64 + sc * 8,
                       &L[buf][1][(nn * 512 + wave * 64) * 8]);
        }
    };

    floatx4 acc[8][4];
    #pragma unroll
    for (int m = 0; m < 8; m++)
        #pragma unroll
        for (int n = 0; n < 4; n++) acc[m][n] = (floatx4){0.f, 0.f, 0.f, 0.f};

    STAGE(0, 0);
    STAGE(1, 1);

    const int NT = K >> 6;
    for (int kt = 0; kt < NT; ++kt) {
        int cur = kt & 1;
        if (kt == NT - 1) wait_vm0(); else wait_vm8();
        __builtin_amdgcn_s_barrier();
        SBAR();

        short8 af[8][2], bf[4][2];
        #pragma unroll
        for (int m = 0; m < 8; m++)
            #pragma unroll
            for (int ks = 0; ks < 2; ks++) {
                int row = wr * 128 + m * 16 + lo;
                int ch = (ks * 4 + quad) ^ (row & 7);
                af[m][ks] = *(const short8*)&L[cur][0][row * 64 + ch * 8];
            }
        #pragma unroll
        for (int n = 0; n < 4; n++)
            #pragma unroll
            for (int ks = 0; ks < 2; ks++) {
                int row = wc * 64 + n * 16 + lo;
                int ch = (ks * 4 + quad) ^ (row & 7);
                bf[n][ks] = *(const short8*)&L[cur][1][row * 64 + ch * 8];
            }
        // k-slot 0 MFMAs overlap k-slot-1 read latency
        #pragma unroll
        for (int m = 0; m < 8; m++)
            #pragma unroll
            for (int n = 0; n < 4; n++)
                acc[m][n] = __builtin_amdgcn_mfma_f32_16x16x32_bf16(af[m][0], bf[n][0], acc[m][n], 0, 0, 0);

        wait_lgkm0();                       // all reads of L[cur] landed in regs
        SBAR();
        __builtin_amdgcn_s_barrier();       // every wave done reading L[cur]
        SBAR();
        if (kt + 2 < NT) STAGE(cur, kt + 2);   // safe overwrite; overlaps k-slot-1 MFMAs

        #pragma unroll
        for (int m = 0; m < 8; m++)
            #pragma unroll
            for (int n = 0; n < 4; n++)
                acc[m][n] = __builtin_amdgcn_mfma_f32_16x16x32_bf16(af[m][1], bf[n][1], acc[m][n], 0, 0, 0);
    }

    if (MODE == 0) {
        #pragma unroll
        for (int m = 0; m < 8; m++)
            #pragma unroll
            for (int n = 0; n < 4; n += 2) {
                int cg = col0 + wc * 64 + n * 16 + lo;
                float bg = bias ? bias[cg] : 0.f;
                float bu = bias ? bias[cg + 16] : 0.f;
                int fc = ((cg >> 5) << 4) + (cg & 15);
                #pragma unroll
                for (int r = 0; r < 4; r++) {
                    int row = row0 + wr * 128 + m * 16 + quad * 4 + r;
                    float vg = acc[m][n][r] + bg;
                    float vu = acc[m][n + 1][r] + bu;
                    float sg = vg / (1.0f + __expf(-vg));
                    outB[(long long)row * (N >> 1) + fc] = f2b(sg * vu);
                }
            }
    } else {
        #pragma unroll
        for (int m = 0; m < 8; m++)
            #pragma unroll
            for (int n = 0; n < 4; n++) {
                int col = col0 + wc * 64 + n * 16 + lo;
                float bv = bias ? bias[col] : 0.f;
                #pragma unroll
                for (int r = 0; r < 4; r++) {
                    int row = row0 + wr * 128 + m * 16 + quad * 4 + r;
                    long long idx = (((long long)(col >> 10) * Mrows + row) << 10) + (col & 1023);
                    outB[idx] = f2b(acc[m][n][r] + bv);
                }
            }
    }
}

// ---------------------------------------------------------------- 128x128 deep-pipeline core
// 256 thr = 4 waves (2x2), BK=64, 64 KiB LDS dbuf (2 blocks/CU), counted vmcnt(8).
__device__ __forceinline__ void core128(
    const unsigned short* __restrict__ Ab, int lda,
    const unsigned short* __restrict__ Bb, int ldb,
    int row0, int col0, int K,
    short (&L)[2][2][128 * 64], floatx4 (&acc)[4][4])
{
    int t = threadIdx.x;
    int wave = t >> 6, lane = t & 63;
    int wr = wave >> 1, wc = wave & 1;
    int quad = lane >> 4, lo = lane & 15;

    const unsigned short* gA = Ab + (long long)row0 * lda;
    const unsigned short* gB = Bb + (long long)col0 * ldb;

    auto STAGE = [&](int buf, int kt) {
        #pragma unroll
        for (int nn = 0; nn < 4; nn++) {
            int c = nn * 256 + t;
            int r = c >> 3, s = c & 7;
            int sc = s ^ (r & 7);
            async_cp16(gA + (long long)r * lda + kt * 64 + sc * 8,
                       &L[buf][0][(nn * 256 + wave * 64) * 8]);
        }
        #pragma unroll
        for (int nn = 0; nn < 4; nn++) {
            int c = nn * 256 + t;
            int r = c >> 3, s = c & 7;
            int sc = s ^ (r & 7);
            async_cp16(gB + (long long)r * ldb + kt * 64 + sc * 8,
                       &L[buf][1][(nn * 256 + wave * 64) * 8]);
        }
    };

    #pragma unroll
    for (int m = 0; m < 4; m++)
        #pragma unroll
        for (int n = 0; n < 4; n++) acc[m][n] = (floatx4){0.f, 0.f, 0.f, 0.f};

    STAGE(0, 0);
    STAGE(1, 1);

    const int NT = K >> 6;
    for (int kt = 0; kt < NT; ++kt) {
        int cur = kt & 1;
        if (kt == NT - 1) wait_vm0(); else wait_vm8();
        __builtin_amdgcn_s_barrier();
        SBAR();

        short8 af[4][2], bf[4][2];
        #pragma unroll
        for (int m = 0; m < 4; m++)
            #pragma unroll
            for (int ks = 0; ks < 2; ks++) {
                int row = wr * 64 + m * 16 + lo;
                int ch = (ks * 4 + quad) ^ (row & 7);
                af[m][ks] = *(const short8*)&L[cur][0][row * 64 + ch * 8];
            }
        #pragma unroll
        for (int n = 0; n < 4; n++)
            #pragma unroll
            for (int ks = 0; ks < 2; ks++) {
                int row = wc * 64 + n * 16 + lo;
                int ch = (ks * 4 + quad) ^ (row & 7);
                bf[n][ks] = *(const short8*)&L[cur][1][row * 64 + ch * 8];
            }
        #pragma unroll
        for (int m = 0; m < 4; m++)
            #pragma unroll
            for (int n = 0; n < 4; n++)
                acc[m][n] = __builtin_amdgcn_mfma_f32_16x16x32_bf16(af[m][0], bf[n][0], acc[m][n], 0, 0, 0);

        wait_lgkm0();
        SBAR();
        __builtin_amdgcn_s_barrier();
        SBAR();
        if (kt + 2 < NT) STAGE(cur, kt + 2);

        #pragma unroll
        for (int m = 0; m < 4; m++)
            #pragma unroll
            for (int n = 0; n < 4; n++)
                acc[m][n] = __builtin_amdgcn_mfma_f32_16x16x32_bf16(af[m][1], bf[n][1], acc[m][n], 0, 0, 0);
    }
}

// z-batched 128x128 pipelined GEMM. z -> (zlo = z & mask, zhi = z >> zLoBits).
// RESID=0: outF fp32 (z strides) and/or outB bf16 (z strides), bias[z*biasZs + col].
// RESID=1: outF[bb*oBS + s*N + col] = acc + bias + resid[same] (batch-mapped rows).
template<int RESID>
__global__ __launch_bounds__(256, 2) void gemm128p(
    const unsigned short* __restrict__ A, long long AzsLo, long long AzsHi, int zLoBits, int lda,
    const unsigned short* __restrict__ BT, long long BzsLo, long long BzsHi, int ldb,
    const float* __restrict__ bias, long long biasZs,
    float* __restrict__ outF, long long OFzsLo, long long OFzsHi,
    unsigned short* __restrict__ outB, long long OBzsLo, long long OBzsHi,
    int K, int N, int rowsPB, long long oBS, const float* __restrict__ resid)
{
    __shared__ short L[2][2][128 * 64];
    int z = blockIdx.z;
    long long zlo = z & ((1 << zLoBits) - 1);
    long long zhi = z >> zLoBits;
    int row0 = blockIdx.y * 128, col0 = blockIdx.x * 128;
    floatx4 acc[4][4];
    core128(A + zlo * AzsLo + zhi * AzsHi, lda,
            BT + zlo * BzsLo + zhi * BzsHi, ldb, row0, col0, K, L, acc);

    int t = threadIdx.x, wave = t >> 6, lane = t & 63;
    int wr = wave >> 1, wc = wave & 1;
    int quad = lane >> 4, lo = lane & 15;
    long long oF0 = zlo * OFzsLo + zhi * OFzsHi;
    long long oB0 = zlo * OBzsLo + zhi * OBzsHi;
    #pragma unroll
    for (int m = 0; m < 4; m++)
        #pragma unroll
        for (int n = 0; n < 4; n++) {
            int col = col0 + wc * 64 + n * 16 + lo;
            float bv = bias ? bias[(long long)z * biasZs + col] : 0.f;
            #pragma unroll
            for (int r = 0; r < 4; r++) {
                int row = row0 + wr * 64 + m * 16 + quad * 4 + r;
                float v = acc[m][n][r] + bv;
                if (RESID) {
                    int bb = row / rowsPB, s = row - bb * rowsPB;
                    long long oi = (long long)bb * oBS + (long long)s * N + col;
                    outF[oi] = v + resid[oi];
                } else {
                    long long idx = (long long)row * N + col;
                    if (outF) outF[oF0 + idx] = v;
                    if (outB) outB[oB0 + idx] = f2b(v);
                }
            }
        }
}

// serial chunk update: gradT = MTbPrev @ KK - KVT; ST = eta*ST - theta*gradT;
// MT = (1-alpha)*MT + ST; MTbNext = bf16(MT). z = batch (4).
__global__ __launch_bounds__(256, 2) void gemm128_mupd(
    const unsigned short* __restrict__ Ap, const unsigned short* __restrict__ Bp,
    const unsigned short* __restrict__ KVT,
    float* __restrict__ ST, float* __restrict__ MT, unsigned short* __restrict__ MTbN,
    const float* __restrict__ lr, const float* __restrict__ mom, const float* __restrict__ fg)
{
    __shared__ short L[2][2][128 * 64];
    int z = blockIdx.z;
    long long zb = (long long)z * D_ * D_;
    int row0 = blockIdx.y * 128, col0 = blockIdx.x * 128;
    floatx4 acc[4][4];
    core128(Ap + zb, D_, Bp + zb, D_, row0, col0, D_, L, acc);

    int t = threadIdx.x, wave = t >> 6, lane = t & 63;
    int wr = wave >> 1, wc = wave & 1;
    int quad = lane >> 4, lo = lane & 15;
    float theta = sigmoidf_(lr[0]) * (1.0f / C_);
    float eta   = sigmoidf_(mom[0]);
    float alpha = sigmoidf_(fg[0]);
    #pragma unroll
    for (int m = 0; m < 4; m++)
        #pragma unroll
        for (int n = 0; n < 4; n++) {
            int col = col0 + wc * 64 + n * 16 + lo;
            #pragma unroll
            for (int r = 0; r < 4; r++) {
                int row = row0 + wr * 64 + m * 16 + quad * 4 + r;
                long long idx = zb + (long long)row * D_ + col;
                float gv = acc[m][n][r] - b2f(KVT[idx]);
                float st = eta * ST[idx] - theta * gv;
                ST[idx] = st;
                float mm = (1.0f - alpha) * MT[idx] + st;
                MT[idx] = mm;
                MTbN[idx] = f2b(mm);
            }
        }
}

// ---------------------------------------------------------------- MFMA flash attention (group-batched)
__global__ __launch_bounds__(256) void attn_mfma(
    const unsigned short* __restrict__ qh, const unsigned short* __restrict__ kh,
    const unsigned short* __restrict__ vh,
    const float* __restrict__ pk, const float* __restrict__ pv,
    unsigned short* __restrict__ ao, int GC)
{
    __shared__ __align__(16) short Ks[64][KP_];
    __shared__ __align__(16) short Vs[64][KP_];
    __shared__ __align__(16) short Ps[4][16][KP_];
    int qb = blockIdx.x, h = blockIdx.y, b = blockIdx.z;
    int q0 = qb * 64;
    int kbase = q0 & ~(C_ - 1);
    int t = threadIdx.x;
    int wave = t >> 6, lane = t & 63;
    int quad = lane >> 4, lo = lane & 15;

    short8 qf[2];
    {
        const unsigned short* qp = qh + (long long)(b * GC + q0 + wave * 16 + lo) * (H_ * DH_)
                                   + h * DH_ + quad * 8;
        qf[0] = *(const short8*)qp;
        qf[1] = *(const short8*)(qp + 32);
    }
    floatx4 o4[4];
    #pragma unroll
    for (int dt = 0; dt < 4; dt++) o4[dt] = (floatx4){0.f, 0.f, 0.f, 0.f};
    float m[4], l[4];
    #pragma unroll
    for (int r = 0; r < 4; r++) { m[r] = -1e30f; l[r] = 0.f; }
    {
        short* pz = &Ps[wave][lo][16 + quad * 4];
        pz[0] = 0; pz[1] = 0; pz[2] = 0; pz[3] = 0;
    }

    int ktmax = ((q0 - kbase) >> 6) + 1;
    for (int kt = 0; kt <= ktmax; kt++) {
        __syncthreads();
        if (kt == 0) {
            int key = t >> 4, d4 = (t & 15) * 4;
            float4 kv4 = *(const float4*)(pk + ((long long)key * H_ + h) * DH_ + d4);
            Ks[key][d4 + 0] = f2b(kv4.x); Ks[key][d4 + 1] = f2b(kv4.y);
            Ks[key][d4 + 2] = f2b(kv4.z); Ks[key][d4 + 3] = f2b(kv4.w);
            float4 vv4 = *(const float4*)(pv + ((long long)key * H_ + h) * DH_ + d4);
            Vs[d4 + 0][key] = f2b(vv4.x); Vs[d4 + 1][key] = f2b(vv4.y);
            Vs[d4 + 2][key] = f2b(vv4.z); Vs[d4 + 3][key] = f2b(vv4.w);
            int dz = t >> 2, kz = 16 + (t & 3) * 4;
            Vs[dz][kz + 0] = 0; Vs[dz][kz + 1] = 0;
            Vs[dz][kz + 2] = 0; Vs[dz][kz + 3] = 0;
        } else {
            int tok0 = kbase + (kt - 1) * 64;
            {
                int key = t >> 2, dblk = (t & 3) * 16;
                const unsigned short* kp2 = kh + (long long)(b * GC + tok0 + key) * (H_ * DH_)
                                            + h * DH_ + dblk;
                *(short8*)&Ks[key][dblk]     = *(const short8*)kp2;
                *(short8*)&Ks[key][dblk + 8] = *(const short8*)(kp2 + 8);
            }
            {
                int kp = t & 31, dg = t >> 5;
                const unsigned short* vp0 = vh + (long long)(b * GC + tok0 + 2 * kp) * (H_ * DH_)
                                            + h * DH_ + dg * 8;
                short8 v0 = *(const short8*)vp0;
                short8 v1 = *(const short8*)(vp0 + H_ * DH_);
                #pragma unroll
                for (int j = 0; j < 8; j++) {
                    unsigned int pk2 = ((unsigned int)(unsigned short)v1[j] << 16)
                                     | (unsigned short)v0[j];
                    *(unsigned int*)&Vs[dg * 8 + j][2 * kp] = pk2;
                }
            }
        }
        __syncthreads();

        int ntiles = (kt == 0) ? 1 : 4;
        floatx4 s4[4];
        #pragma unroll
        for (int nt = 0; nt < 4; nt++) {
            if (nt >= ntiles) break;
            s4[nt] = (floatx4){0.f, 0.f, 0.f, 0.f};
            #pragma unroll
            for (int ks = 0; ks < 2; ks++) {
                short8 bfr = *(const short8*)&Ks[nt * 16 + lo][ks * 32 + quad * 8];
                s4[nt] = __builtin_amdgcn_mfma_f32_16x16x32_bf16(qf[ks], bfr, s4[nt], 0, 0, 0);
            }
        }
        bool diag = (kt == ktmax);
        int key0 = kbase + (kt - 1) * 64;
        #pragma unroll
        for (int nt = 0; nt < 4; nt++) {
            if (nt >= ntiles) break;
            #pragma unroll
            for (int r = 0; r < 4; r++) {
                float v = s4[nt][r] * 0.125f;
                if (diag) {
                    int kg = key0 + nt * 16 + lo;
                    int qq = q0 + wave * 16 + quad * 4 + r;
                    if (kg > qq) v = -1e30f;
                }
                s4[nt][r] = v;
            }
        }
        float alpha[4];
        #pragma unroll
        for (int r = 0; r < 4; r++) {
            float tm = s4[0][r];
            #pragma unroll
            for (int nt = 1; nt < 4; nt++) { if (nt >= ntiles) break; tm = fmaxf(tm, s4[nt][r]); }
            #pragma unroll
            for (int msk = 1; msk <= 8; msk <<= 1) tm = fmaxf(tm, __shfl_xor(tm, msk, 64));
            float mn = fmaxf(m[r], tm);
            alpha[r] = __expf(m[r] - mn);
            float sum = 0.f;
            #pragma unroll
            for (int nt = 0; nt < 4; nt++) {
                if (nt >= ntiles) break;
                float p = __expf(s4[nt][r] - mn);
                sum += p;
                Ps[wave][quad * 4 + r][nt * 16 + lo] = f2b(p);
            }
            #pragma unroll
            for (int msk = 1; msk <= 8; msk <<= 1) sum += __shfl_xor(sum, msk, 64);
            l[r] = l[r] * alpha[r] + sum;
            m[r] = mn;
        }
        #pragma unroll
        for (int dt = 0; dt < 4; dt++)
            #pragma unroll
            for (int r = 0; r < 4; r++) o4[dt][r] *= alpha[r];
        __syncthreads();
        int ksteps = (kt == 0) ? 1 : 2;
        #pragma unroll
        for (int ks = 0; ks < 2; ks++) {
            if (ks >= ksteps) break;
            short8 afr = *(const short8*)&Ps[wave][lo][ks * 32 + quad * 8];
            #pragma unroll
            for (int dt = 0; dt < 4; dt++) {
                short8 bfr = *(const short8*)&Vs[dt * 16 + lo][ks * 32 + quad * 8];
                o4[dt] = __builtin_amdgcn_mfma_f32_16x16x32_bf16(afr, bfr, o4[dt], 0, 0, 0);
            }
        }
    }
    #pragma unroll
    for (int r = 0; r < 4; r++) {
        float inv = 1.0f / l[r];
        int q = q0 + wave * 16 + quad * 4 + r;
        unsigned short* aop = ao + (long long)(b * GC + q) * (H_ * DH_) + h * DH_ + lo;
        #pragma unroll
        for (int dt = 0; dt < 4; dt++) aop[dt * 16] = f2b(o4[dt][r] * inv);
    }
}

// ---------------------------------------------------------------- launch
extern "C" void kernel_launch(void* const* d_in, const int* in_sizes, int n_in,
                              void* d_out, int out_size, void* d_ws, size_t ws_size,
                              hipStream_t stream)
{
    const float* x     = (const float*)d_in[0];
    const float* g1    = (const float*)d_in[1];
    const float* b1    = (const float*)d_in[2];
    const float* g2    = (const float*)d_in[3];
    const float* b2    = (const float*)d_in[4];
    const float* g3    = (const float*)d_in[5];
    const float* b3    = (const float*)d_in[6];
    const float* Wqm   = (const float*)d_in[7];
    const float* Wkm   = (const float*)d_in[8];
    const float* Wvm   = (const float*)d_in[9];
    const float* lr    = (const float*)d_in[10];
    const float* mom   = (const float*)d_in[11];
    const float* fg    = (const float*)d_in[12];
    const float* Wq    = (const float*)d_in[13];
    const float* bq    = (const float*)d_in[14];
    const float* Wk    = (const float*)d_in[15];
    const float* bk    = (const float*)d_in[16];
    const float* Wv    = (const float*)d_in[17];
    const float* bv    = (const float*)d_in[18];
    const float* Wo    = (const float*)d_in[19];
    const float* bo    = (const float*)d_in[20];
    const float* pk    = (const float*)d_in[21];
    const float* pv    = (const float*)d_in[22];
    const float* Wg    = (const float*)d_in[23];
    const float* bg    = (const float*)d_in[24];
    const float* Wgate = (const float*)d_in[25];
    const float* bgate = (const float*)d_in[26];
    const float* Wup   = (const float*)d_in[27];
    const float* bup   = (const float*)d_in[28];
    const float* Wdown = (const float*)d_in[29];
    const float* bdown = (const float*)d_in[30];
    float* out = (float*)d_out;

    const long long MiB = 1024LL * 1024LL;
    const long long D2 = (long long)D_ * D_;
    char* w = (char*)d_ws;

    // ---- group size: total = 82 + 52*G MiB (G in {8,4,2,1}); mctx is bf16-only now
    int G = 8;
    while (G > 1 && (size_t)((82 + 52 * G) * MiB) > ws_size) G >>= 1;
    const int GC = G * C_;
    const int NG = NC_ / G;
    const int RG = B_ * GC;
    const int RING = G + 1;
    int gcShift = 0; while ((1 << gcShift) < GC) gcShift++;
    const long long GiM = (long long)G * MiB;

    // ---- fixed region
    float* MT  = (float*)(w + 0 * MiB);                          // 16
    float* ST  = (float*)(w + 16 * MiB);                         // 16
    unsigned short* MTb = (unsigned short*)(w + 32 * MiB);       // 8*(G+1) ring of bf16 M^T
    char* wt = w + (32 + 8 * (long long)RING) * MiB;
    unsigned short* WqkvmT = (unsigned short*)(wt + 0 * MiB);    // 6
    unsigned short* WqkvhT = (unsigned short*)(wt + 6 * MiB);    // 6
    unsigned short* WoT    = (unsigned short*)(wt + 12 * MiB);   // 2
    unsigned short* WgT    = (unsigned short*)(wt + 14 * MiB);   // 2
    unsigned short* WffT   = (unsigned short*)(wt + 16 * MiB);   // 16 [8192][1024] 16-col-pair interleave
    unsigned short* WdownT = (unsigned short*)(wt + 32 * MiB);   // 8
    float* bqkvh = (float*)(wt + 40 * MiB);                      // 12 KB
    float* bffI  = (float*)(wt + 40 * MiB + 65536);              // 32 KB interleaved
    float* bog   = (float*)(wt + 40 * MiB + 131072);             // 8 KB
    char* gbase = wt + 41 * MiB;

    // ---- group region (G·MiB units): QKVm 12 | kmT 4 | vmT 4 | KK 8 | KVT 8 | mctx16 4 | LNout 4 = 44G
    unsigned short* QKVm   = (unsigned short*)(gbase);                 // qm|km|vm, later qh|kh|vh
    unsigned short* kmTG   = (unsigned short*)(gbase + 12 * GiM);      // [b][D][GC]; later Hao
    unsigned short* vmTG   = (unsigned short*)(gbase + 16 * GiM);      // [b][D][GC]
    unsigned short* KK     = (unsigned short*)(gbase + 20 * GiM);      // [j][b][D][D] bf16
    unsigned short* KVT    = (unsigned short*)(gbase + 28 * GiM);      // [j][b][D][D] bf16
    unsigned short* mctx16 = (unsigned short*)(gbase + 36 * GiM);      // bf16 mem_ctx (sole copy)
    unsigned short* LNout  = (unsigned short*)(gbase + 40 * GiM);
    // overlays (dead-by-then regions)
    unsigned short* Hao = kmTG;
    float* aoW = (float*)KK;       // tail: 8G fp32
    float* gG  = (float*)KVT;      // tail: 8G fp32
    unsigned short* G0 = QKVm;     // FFN prod 16G (QKVm+kmT)

    hipMemsetAsync(d_ws, 0, (size_t)((32 + 8 * (long long)RING) * MiB), stream);  // MT, ST, MTb ring

    // concat / interleave biases
    hipMemcpyAsync(bqkvh,        bq, 4096, hipMemcpyDeviceToDevice, stream);
    hipMemcpyAsync(bqkvh + 1024, bk, 4096, hipMemcpyDeviceToDevice, stream);
    hipMemcpyAsync(bqkvh + 2048, bv, 4096, hipMemcpyDeviceToDevice, stream);
    hipMemcpyAsync(bog,          bo, 4096, hipMemcpyDeviceToDevice, stream);
    hipMemcpyAsync(bog + 1024,   bg, 4096, hipMemcpyDeviceToDevice, stream);
    interleave16<<<16, 256, 0, stream>>>(bgate, bup, bffI, FF_);

    // weight transposes -> bf16 [N][K]; Wgate/Wup 16-col-pair interleaved into WffT
    transpose_f32_b16<<<dim3(32, 32, 1), 256, 0, stream>>>(Wqm, WqkvmT,           D_, D_, 0, 0, 16, 0);
    transpose_f32_b16<<<dim3(32, 32, 1), 256, 0, stream>>>(Wkm, WqkvmT + 1048576, D_, D_, 0, 0, 16, 0);
    transpose_f32_b16<<<dim3(32, 32, 1), 256, 0, stream>>>(Wvm, WqkvmT + 2097152, D_, D_, 0, 0, 16, 0);
    transpose_f32_b16<<<dim3(32, 32, 1), 256, 0, stream>>>(Wq,  WqkvhT,           D_, D_, 0, 0, 16, 0);
    transpose_f32_b16<<<dim3(32, 32, 1), 256, 0, stream>>>(Wk,  WqkvhT + 1048576, D_, D_, 0, 0, 16, 0);
    transpose_f32_b16<<<dim3(32, 32, 1), 256, 0, stream>>>(Wv,  WqkvhT + 2097152, D_, D_, 0, 0, 16, 0);
    transpose_f32_b16<<<dim3(32, 32, 1), 256, 0, stream>>>(Wo,  WoT,              D_, D_, 0, 0, 16, 0);
    transpose_f32_b16<<<dim3(32, 32, 1), 256, 0, stream>>>(Wg,  WgT,              D_, D_, 0, 0, 16, 0);
    transpose_f32_b16<<<dim3(128, 32, 1), 256, 0, stream>>>(Wgate, WffT,          D_, FF_, 0, 0, 32, 0);
    transpose_f32_b16<<<dim3(128, 32, 1), 256, 0, stream>>>(Wup,   WffT,          D_, FF_, 0, 0, 32, 16);
    transpose_f32_b16<<<dim3(32, 128, 1), 256, 0, stream>>>(Wdown, WdownT,        FF_, D_, 0, 0, 16, 0);

    const long long xBS = (long long)S_ * D_;

    for (int g = 0; g < NG; g++) {
        const float* xg = x   + (long long)g * GC * D_;
        float* og       = out + (long long)g * GC * D_;
        int s0 = (g * G) % RING;

        // A) h1 = LN1(x) -> LNout
        ln_kernel<<<RG, 256, 0, stream>>>(xg, xBS, GC, nullptr, nullptr, g1, b1, LNout);
        // B) qm|km|vm -> QKVm (col-split slots of [RG][1024])
        gemm256<1><<<dim3(12, RG / 256), 512, 0, stream>>>(LNout, WqkvmT, nullptr, QKVm, D_, 3072, RG);
        // C) km normalize; kmT, vmT -> [b][D][GC]
        rownorm_b16<<<RG, 256, 0, stream>>>(QKVm + (long long)RG * D_);
        transpose_b16_b16<<<dim3(32, GC / 32, 4), 256, 0, stream>>>(QKVm + (long long)RG * D_,
            kmTG, GC, D_, (long long)GC * D_, (long long)D_ * GC);
        transpose_b16_b16<<<dim3(32, GC / 32, 4), 256, 0, stream>>>(QKVm + 2LL * RG * D_,
            vmTG, GC, D_, (long long)GC * D_, (long long)D_ * GC);
        // D1) KK[j][b] = kmT_j . km_j  (zlo=b, zhi=j)
        gemm128p<0><<<dim3(8, 8, 4 * G), 256, 0, stream>>>(
            kmTG, (long long)D_ * GC, (long long)C_, 2, GC,
            kmTG, (long long)D_ * GC, (long long)C_, GC,
            nullptr, 0,
            nullptr, 0, 0,
            KK, D2, 4 * D2,
            C_, D_, 0, 0, nullptr);
        // D2) KVT[j][b] = vmT_j . km_j
        gemm128p<0><<<dim3(8, 8, 4 * G), 256, 0, stream>>>(
            vmTG, (long long)D_ * GC, (long long)C_, 2, GC,
            kmTG, (long long)D_ * GC, (long long)C_, GC,
            nullptr, 0,
            nullptr, 0, 0,
            KVT, D2, 4 * D2,
            C_, D_, 0, 0, nullptr);
        // D3) serial chain: one fused GEMM+update per chunk
        for (int j = 0; j < G; j++) {
            int sp = (s0 + j) % RING, sn = (s0 + j + 1) % RING;
            gemm128_mupd<<<dim3(8, 8, 4), 256, 0, stream>>>(
                MTb + (long long)sp * 4 * D2, KK + (long long)j * 4 * D2,
                KVT + (long long)j * 4 * D2, ST, MT, MTb + (long long)sn * 4 * D2,
                lr, mom, fg);
        }
        // D4) mem_ctx = qm_j @ M_{j-1} -> mctx16 (bf16 only)
        if (G <= 2) {
            long long stride = (G == 2) ? (((s0 + 1) % RING) - s0) : 0;
            gemm128p<0><<<dim3(8, 4, 4 * G), 256, 0, stream>>>(
                QKVm, (long long)GC * D_, (long long)C_ * D_, 2, D_,
                MTb + (long long)s0 * 4 * D2, D2, stride * 4 * D2, D_,
                nullptr, 0,
                nullptr, 0, 0,
                mctx16, (long long)GC * D_, (long long)C_ * D_,
                D_, D_, 0, 0, nullptr);
        } else {
            for (int j = 0; j < G; j++) {
                int sp = (s0 + j) % RING;
                gemm128p<0><<<dim3(8, 4, 4), 256, 0, stream>>>(
                    QKVm + (long long)j * C_ * D_, (long long)GC * D_, 0, 2, D_,
                    MTb + (long long)sp * 4 * D2, D2, 0, D_,
                    nullptr, 0,
                    nullptr, 0, 0,
                    mctx16 + (long long)j * C_ * D_, (long long)GC * D_, 0,
                    D_, D_, 0, 0, nullptr);
            }
        }
        // E) h2 = LN2(x + mem_ctx) -> LNout (bf16 addend)
        ln_kernel<<<RG, 256, 0, stream>>>(xg, xBS, GC, nullptr, mctx16, g2, b2, LNout);
        // F) qh|kh|vh -> QKVm
        gemm256<1><<<dim3(12, RG / 256), 512, 0, stream>>>(LNout, WqkvhT, bqkvh, QKVm, D_, 3072, RG);
        // G) attention -> Hao
        attn_mfma<<<dim3(GC / 64, H_, B_), 256, 0, stream>>>(QKVm, QKVm + (long long)RG * D_,
            QKVm + 2LL * RG * D_, pk, pv, Hao, GC);
        // H+I) z=0: aoW = Hao@Wo+bo ; z=1: gG = mctx16@Wg+bg
        gemm128p<0><<<dim3(8, RG / 128, 2), 256, 0, stream>>>(
            Hao, (long long)(mctx16 - Hao), 0, 30, D_,
            WoT, (long long)(WgT - WoT), 0, D_,
            bog, 1024,
            aoW, (long long)(gG - aoW), 0,
            nullptr, 0, 0,
            D_, D_, 0, 0, nullptr);
        // J) fused gate-combine + LN3 -> og, LNout (mctx bf16)
        gate_ln_kernel<<<RG, 256, 0, stream>>>(xg, xBS, gcShift, gG, aoW, mctx16,
            g3, b3, og, LNout);
        // L) FFN gate|up 16-pair interleaved, fused silu*up -> G0 [RG][4096] bf16
        gemm256<0><<<dim3(32, RG / 256), 512, 0, stream>>>(LNout, WffT, bffI, G0, D_, 8192, 0);
        // N) out = o + prod @ Wdown + bdown
        gemm128p<1><<<dim3(8, RG / 128, 1), 256, 0, stream>>>(
            G0, 0, 0, 0, FF_,
            WdownT, 0, 0, FF_,
            bdown, 0,
            og, 0, 0,
            nullptr, 0, 0,
            FF_, D_, GC, xBS, og);
    }
}